// Round 8
// baseline (306.975 us; speedup 1.0000x reference)
//
#include <hip/hip_runtime.h>
#include <hip/hip_bf16.h>

typedef __attribute__((ext_vector_type(8))) short bf16x8;
typedef __attribute__((ext_vector_type(4))) float f32x4;

#define B_   4
#define T_   2048
#define DIM_ 1024
#define H_   64
#define NS_  32
#define K_   8
#define HV_  32
#define NTOK  (B_ * T_)   /* 8192 */
#define RA_N  128         /* router logits(64) | a(64) */
#define CL_   64          /* scan chunk length */
#define NC_   (T_ / CL_)  /* 32 chunks per slot */
#define NSLOT (B_ * K_)   /* 32 */
#define NPAIR (NTOK * K_) /* 65536 */
#define NWIN  32          /* bucketing windows (2048 pairs = 256 tokens each) */

// ---------------------------------------------------------------- helpers
__device__ __forceinline__ void gld_lds16(const void* g, void* s) {
  __builtin_amdgcn_global_load_lds(
      (const __attribute__((address_space(1))) void*)g,
      (__attribute__((address_space(3))) void*)s, 16, 0, 0);
}
__device__ __forceinline__ float silu_f(float x) { return x / (1.f + expf(-x)); }

// ---------------------------------------------------------------- prep
__global__ __launch_bounds__(256) void cast_bf16(const float* __restrict__ in,
                                                 __hip_bfloat16* __restrict__ out, int n4) {
  int i = blockIdx.x * 256 + threadIdx.x;
  if (i >= n4) return;
  const float4 v = *(const float4*)(in + (size_t)i * 4);
  union { short4 s4; __hip_bfloat16 h[4]; } u;
  u.h[0] = __float2bfloat16(v.x); u.h[1] = __float2bfloat16(v.y);
  u.h[2] = __float2bfloat16(v.z); u.h[3] = __float2bfloat16(v.w);
  *(short4*)(out + (size_t)i * 4) = u.s4;
}

// Wg[h][r][d], r<32: Wq[h*32+r], r<64: Wk[h*32+r-32], else Wv[h*32+r-64]  (bf16)
__global__ __launch_bounds__(256) void build_wg(const float* __restrict__ Wq,
                                                const float* __restrict__ Wk,
                                                const float* __restrict__ Wv,
                                                __hip_bfloat16* __restrict__ Wg) {
  int i = blockIdx.x * 256 + threadIdx.x;           // 6144*1024/4
  int row = i >> 8, c4 = (i & 255) * 4;
  int h = row / 96, r = row - h * 96;
  const float* src = (r < 32) ? (Wq + ((size_t)h * 32 + r) * 1024)
                   : (r < 64) ? (Wk + ((size_t)h * 32 + r - 32) * 1024)
                              : (Wv + ((size_t)h * 32 + r - 64) * 1024);
  const float4 v = *(const float4*)(src + c4);
  union { short4 s4; __hip_bfloat16 hh[4]; } u;
  u.hh[0] = __float2bfloat16(v.x); u.hh[1] = __float2bfloat16(v.y);
  u.hh[2] = __float2bfloat16(v.z); u.hh[3] = __float2bfloat16(v.w);
  *(short4*)(Wg + (size_t)row * 1024 + c4) = u.s4;
}

// B2[d][s*32+v] = Wo[d][v]  (slot-replicated Wo, bf16), 1024x256
__global__ __launch_bounds__(256) void build_b2(const float* __restrict__ Wo,
                                                __hip_bfloat16* __restrict__ B2) {
  int i = blockIdx.x * 256 + threadIdx.x;
  int d = i >> 8, c = i & 255;
  B2[i] = __float2bfloat16(Wo[d * 32 + (c & 31)]);
}

// WT[d][h] = (h<64 ? Wr : Wa)[h][d]   fp32, 1024x128
__global__ __launch_bounds__(256) void build_wt(const float* __restrict__ Wr,
                                                const float* __restrict__ Wa,
                                                float* __restrict__ WT) {
  int i = blockIdx.x * 256 + threadIdx.x;
  int d = i >> 7, h = i & 127;
  WT[i] = (h < 64) ? Wr[h * 1024 + d] : Wa[(h - 64) * 1024 + d];
}

// ---------------------------------------------------------------- router GEMM (fp32 exact, split-K x2)
__global__ __launch_bounds__(256) void router_gemm(const float* __restrict__ x,
                                                   const float* __restrict__ WT,
                                                   float* __restrict__ RA) {
  __shared__ float Lp[4][8][128];
  const int w = threadIdx.x >> 6, l = threadIdx.x & 63;
  const int t0 = blockIdx.x * 16 + (w >> 1) * 8;
  const int d0 = (w & 1) * 512;
  float a0[8] = {}, a1[8] = {};
  for (int d = d0; d < d0 + 512; d += 4) {
    float4 xv[8];
#pragma unroll
    for (int i = 0; i < 8; ++i) xv[i] = *(const float4*)(x + (size_t)(t0 + i) * DIM_ + d);
#pragma unroll
    for (int j = 0; j < 4; ++j) {
      const float w0 = WT[(d + j) * RA_N + l];
      const float w1 = WT[(d + j) * RA_N + 64 + l];
#pragma unroll
      for (int i = 0; i < 8; ++i) {
        const float xs = ((const float*)&xv[i])[j];
        a0[i] = fmaf(xs, w0, a0[i]);
        a1[i] = fmaf(xs, w1, a1[i]);
      }
    }
  }
#pragma unroll
  for (int i = 0; i < 8; ++i) { Lp[w][i][l] = a0[i]; Lp[w][i][64 + l] = a1[i]; }
  __syncthreads();
  for (int o = threadIdx.x; o < 2048; o += 256) {
    const int ti = o >> 7, cc = o & 127;
    const int wp = (ti >> 3) * 2;
    RA[(size_t)(blockIdx.x * 16 + ti) * RA_N + cc] = Lp[wp][ti & 7][cc] + Lp[wp + 1][ti & 7][cc];
  }
}

// ---------------------------------------------------------------- top-k + decay (1 wave / token)
__global__ __launch_bounds__(256) void router_topk(const float* __restrict__ RA,
                                                   const float* __restrict__ A_log,
                                                   const float* __restrict__ dt_bias,
                                                   int* __restrict__ idxb,
                                                   float* __restrict__ rwb,
                                                   float* __restrict__ decb) {
  const int w = threadIdx.x >> 6, l = threadIdx.x & 63;
  const int m = blockIdx.x * 4 + w;
  float zcur = RA[(size_t)m * RA_N + l];
  const int idx = l;
  float z0 = 0.f, myz = 0.f;
  int myh = 0;
#pragma unroll
  for (int i = 0; i < 8; ++i) {
    float v = zcur; int vi = idx;
#pragma unroll
    for (int off = 1; off < 64; off <<= 1) {
      float ov = __shfl_xor(v, off);
      int   oi = __shfl_xor(vi, off);
      if (ov > v || (ov == v && oi < vi)) { v = ov; vi = oi; }
    }
    if (i == 0) z0 = v;
    if (l == i) { myz = v; myh = vi; }
    if (idx == vi) zcur = -__builtin_inff();
  }
  float e = (l < 8) ? expf(myz - z0) : 0.f;
  float es = e;
  es += __shfl_xor(es, 1); es += __shfl_xor(es, 2); es += __shfl_xor(es, 4);
  if (l < 8) {
    const float a  = RA[(size_t)m * RA_N + 64 + myh];
    const float xb = a + dt_bias[myh];
    const float dt = (xb > 20.f) ? xb : log1pf(expf(xb));
    idxb[m * 8 + l] = myh;
    rwb [m * 8 + l] = e / es;
    decb[m * 8 + l] = expf(-expf(A_log[myh]) * dt);
  }
}

// ---------------------------------------------------------------- window-sorted head bucketing
// Window w = pairs [w*2048,(w+1)*2048) = 256 consecutive tokens. Three stages
// give pairtok[h] ordered by window (deterministic window boundaries; order
// inside a window nondeterministic, which is harmless: rec rows are keyed by
// pair id). This makes chunk c of EVERY head cover the same ~512-token span,
// so token-affine XCD mapping keeps the x-gather L2-resident.
__global__ __launch_bounds__(256) void hist_count(const int* __restrict__ idxb,
                                                  int* __restrict__ wcnt) {
  __shared__ int lh[H_];
  const int tid = threadIdx.x;
  if (tid < H_) lh[tid] = 0;
  __syncthreads();
  const int base = blockIdx.x * (NPAIR / NWIN);
#pragma unroll
  for (int j = 0; j < 8; ++j) atomicAdd(&lh[idxb[base + j * 256 + tid]], 1);
  __syncthreads();
  if (tid < H_) wcnt[blockIdx.x * H_ + tid] = lh[tid];
}

__global__ void hist_scan(const int* __restrict__ wcnt,
                          int* __restrict__ wbase, int* __restrict__ cnt) {
  const int h = threadIdx.x;
  if (h >= H_) return;
  int run = 0;
  for (int w = 0; w < NWIN; ++w) { wbase[w * H_ + h] = run; run += wcnt[w * H_ + h]; }
  cnt[h] = run;
}

__global__ __launch_bounds__(256) void hist_place(const int* __restrict__ idxb,
                                                  const int* __restrict__ wbase,
                                                  int* __restrict__ pairtok) {
  __shared__ int lcur[H_];
  const int tid = threadIdx.x;
  if (tid < H_) lcur[tid] = wbase[blockIdx.x * H_ + tid];
  __syncthreads();
  const int base = blockIdx.x * (NPAIR / NWIN);
#pragma unroll
  for (int j = 0; j < 8; ++j) {
    const int pid = base + j * 256 + tid;
    const int h = idxb[pid];
    const int pos = atomicAdd(&lcur[h], 1);
    pairtok[h * NTOK + pos] = pid;
  }
}

// ---------------------------------------------------------------- grouped QKV projection
// 64-row blocks, 4 waves = 2 row-groups x 2 K-halves (split-K), direct
// register fragments, LDS cross-K reduction. Token-affine XCD mapping:
// h = bid>>7, c = bid&127 -> XCD = c%8; with window-sorted pairtok each XCD's
// x working set is ~2MB (L2-resident); weights stream sequentially from L3.
__global__ __launch_bounds__(256, 4) void grouped_qkv(const short* __restrict__ x_bf,
                                                      const short* __restrict__ Wg,
                                                      const int* __restrict__ pairtok,
                                                      const int* __restrict__ cnt,
                                                      const float* __restrict__ rwb,
                                                      const float* __restrict__ decb,
                                                      float* __restrict__ rec) {
  const int bid = blockIdx.x;
  const int h = bid >> 7;                             // 64 heads
  const int c = bid & 127;                            // token-window chunk
  const int n = cnt[h];
  if (c * 64 >= n) return;
  __shared__ int prs[64];
  __shared__ __align__(16) float red[64 * 97];        // ~24.8 KB reduction buffer
  if (threadIdx.x < 64) {
    const int ri = c * 64 + threadIdx.x;
    prs[threadIdx.x] = (ri < n) ? pairtok[h * NTOK + ri] : -1;
  }
  __syncthreads();

  const int w = threadIdx.x >> 6, l = threadIdx.x & 63;
  const int wr = w >> 1, wk = w & 1;                  // row-group, K-half
  const int lr = l & 15, lk = l >> 4;
  const int rowbase = wr * 32;
  const int fallback = prs[0] >> 3;
  const int p0 = prs[rowbase + lr], p1 = prs[rowbase + 16 + lr];
  const long tok0 = (p0 >= 0) ? (long)(p0 >> 3) : fallback;
  const long tok1 = (p1 >= 0) ? (long)(p1 >> 3) : fallback;
  const short* a0p = x_bf + tok0 * DIM_ + wk * 512 + lk * 8;
  const short* a1p = x_bf + tok1 * DIM_ + wk * 512 + lk * 8;
  const short* bp  = Wg + ((size_t)h * 96 + lr) * DIM_ + wk * 512 + lk * 8;

  f32x4 acc[2][6] = {};
  bf16x8 a0c = *(const bf16x8*)a0p;
  bf16x8 a1c = *(const bf16x8*)a1p;
  bf16x8 bc[6];
#pragma unroll
  for (int j = 0; j < 6; ++j) bc[j] = *(const bf16x8*)(bp + (size_t)j * 16 * DIM_);

#pragma unroll 5
  for (int k0 = 32; k0 < 512; k0 += 32) {
    const bf16x8 a0n = *(const bf16x8*)(a0p + k0);
    const bf16x8 a1n = *(const bf16x8*)(a1p + k0);
    bf16x8 bn[6];
#pragma unroll
    for (int j = 0; j < 6; ++j) bn[j] = *(const bf16x8*)(bp + (size_t)j * 16 * DIM_ + k0);
#pragma unroll
    for (int j = 0; j < 6; ++j) {
      acc[0][j] = __builtin_amdgcn_mfma_f32_16x16x32_bf16(a0c, bc[j], acc[0][j], 0, 0, 0);
      acc[1][j] = __builtin_amdgcn_mfma_f32_16x16x32_bf16(a1c, bc[j], acc[1][j], 0, 0, 0);
    }
    a0c = a0n; a1c = a1n;
#pragma unroll
    for (int j = 0; j < 6; ++j) bc[j] = bn[j];
  }
#pragma unroll
  for (int j = 0; j < 6; ++j) {                       // tail K-step
    acc[0][j] = __builtin_amdgcn_mfma_f32_16x16x32_bf16(a0c, bc[j], acc[0][j], 0, 0, 0);
    acc[1][j] = __builtin_amdgcn_mfma_f32_16x16x32_bf16(a1c, bc[j], acc[1][j], 0, 0, 0);
  }

  // cross-K reduction: wk=1 dumps, wk=0 accumulates
  if (wk) {
#pragma unroll
    for (int i = 0; i < 2; ++i)
#pragma unroll
      for (int j = 0; j < 6; ++j)
#pragma unroll
        for (int r = 0; r < 4; ++r)
          red[(rowbase + i * 16 + lk * 4 + r) * 97 + j * 16 + lr] = acc[i][j][r];
  }
  __syncthreads();
  if (wk == 0) {
#pragma unroll
    for (int i = 0; i < 2; ++i)
#pragma unroll
      for (int j = 0; j < 6; ++j)
#pragma unroll
        for (int r = 0; r < 4; ++r)
          acc[i][j][r] += red[(rowbase + i * 16 + lk * 4 + r) * 97 + j * 16 + lr];

    // epilogue: cols j0,j1=q j2,j3=k j4,j5=v ; row = rowbase + i*16 + lk*4 + r
#pragma unroll
    for (int i = 0; i < 2; ++i) {
#pragma unroll
      for (int r = 0; r < 4; ++r) {
        const int row = rowbase + i * 16 + lk * 4 + r;
        const int p = prs[row];
        float q0v = silu_f(acc[i][0][r]), q1v = silu_f(acc[i][1][r]);
        float k0v = silu_f(acc[i][2][r]), k1v = silu_f(acc[i][3][r]);
        float v0 = silu_f(acc[i][4][r]), v1 = silu_f(acc[i][5][r]);
        float ssq = q0v * q0v + q1v * q1v;
        float ssk = k0v * k0v + k1v * k1v;
        ssq += __shfl_xor(ssq, 1); ssq += __shfl_xor(ssq, 2);
        ssq += __shfl_xor(ssq, 4); ssq += __shfl_xor(ssq, 8);
        ssk += __shfl_xor(ssk, 1); ssk += __shfl_xor(ssk, 2);
        ssk += __shfl_xor(ssk, 4); ssk += __shfl_xor(ssk, 8);
        const float rq = rsqrtf(ssq + 1e-6f), rk = rsqrtf(ssk + 1e-6f);
        if (p >= 0) {
          const int m = p >> 3, s = p & 7;
          const int b = m >> 11, t = m & (T_ - 1);
          float* rb = rec + (((size_t)(b * 8 + s)) * T_ + t) * 128;
          rb[lr]      = k0v * rk;
          rb[16 + lr] = k1v * rk;
          rb[32 + lr] = q0v * rq;
          rb[48 + lr] = q1v * rq;
          rb[64 + lr] = v0;
          rb[80 + lr] = v1;
          if (lr == 0) { rb[96] = decb[p]; rb[97] = rwb[p]; }
        }
      }
    }
  }
}

// ---------------------------------------------------------------- bf16 MFMA GEMM, C = A * B^T (final proj)
template <bool OUT_BF16>
__global__ __launch_bounds__(256) void gemm_bt(const short* __restrict__ A,
                                               const short* __restrict__ Bm,
                                               void* __restrict__ Cout,
                                               int M, int N, int K) {
  __shared__ __align__(16) short As[2][128 * 32];
  __shared__ __align__(16) short Bs[2][128 * 32];
  const int tid = threadIdx.x;
  const int w = tid >> 6, l = tid & 63;
  const int m0 = blockIdx.y * 128, n0 = blockIdx.x * 128;
  const int wr = (w >> 1) * 64, wc = (w & 1) * 64;
  const int rsub = l >> 2, csub = (l & 3) * 8;
  const int lr = l & 15, lk = l >> 4;
  f32x4 acc[4][4] = {};

  auto STAGE = [&](int buf, int k0) {
#pragma unroll
    for (int j = 0; j < 2; ++j) {
      const int ra = w * 32 + j * 16;
      gld_lds16(A  + (size_t)(m0 + ra + rsub) * K + k0 + csub, As[buf] + ra * 32);
      gld_lds16(Bm + (size_t)(n0 + ra + rsub) * K + k0 + csub, Bs[buf] + ra * 32);
    }
  };

  STAGE(0, 0);
  __syncthreads();
  int cur = 0;
  for (int k0 = 0; k0 < K; k0 += 32) {
    if (k0 + 32 < K) STAGE(cur ^ 1, k0 + 32);
    bf16x8 af[4], bfr[4];
#pragma unroll
    for (int i = 0; i < 4; ++i) af[i]  = *(const bf16x8*)(As[cur] + (wr + i * 16 + lr) * 32 + lk * 8);
#pragma unroll
    for (int j = 0; j < 4; ++j) bfr[j] = *(const bf16x8*)(Bs[cur] + (wc + j * 16 + lr) * 32 + lk * 8);
#pragma unroll
    for (int i = 0; i < 4; ++i)
#pragma unroll
      for (int j = 0; j < 4; ++j)
        acc[i][j] = __builtin_amdgcn_mfma_f32_16x16x32_bf16(af[i], bfr[j], acc[i][j], 0, 0, 0);
    __syncthreads();
    cur ^= 1;
  }
#pragma unroll
  for (int i = 0; i < 4; ++i)
#pragma unroll
    for (int j = 0; j < 4; ++j) {
      const size_t row0 = (size_t)m0 + wr + i * 16 + lk * 4;
      const size_t col  = (size_t)n0 + wc + j * 16 + lr;
#pragma unroll
      for (int r = 0; r < 4; ++r) {
        if constexpr (OUT_BF16)
          ((__hip_bfloat16*)Cout)[(row0 + r) * N + col] = __float2bfloat16(acc[i][j][r]);
        else
          ((float*)Cout)[(row0 + r) * N + col] = acc[i][j][r];
      }
    }
}

// ---------------------------------------------------------------- chunked scan: pass 1
__global__ __launch_bounds__(256) void scan_pass1(const float* __restrict__ rec,
                                                  float* __restrict__ ylocal,
                                                  float* __restrict__ Sloc,
                                                  float* __restrict__ Pc,
                                                  float* __restrict__ cumd) {
  __shared__ __align__(16) float R[CL_ * 128];   // 32 KB
  const int blk = blockIdx.x;
  const int bs = blk >> 5, c = blk & (NC_ - 1);
  const int t0 = c * CL_;
  const float* g = rec + ((size_t)bs * T_ + t0) * 128;
  for (int i = threadIdx.x; i < CL_ * 32; i += 256)
    *(float4*)(R + (size_t)i * 4) = *(const float4*)(g + (size_t)i * 4);
  __syncthreads();

  const int w = threadIdx.x >> 6, l = threadIdx.x & 63;
  const int v = w * 8 + (l & 7);
  const int n0 = (l >> 3) * 4;
  float s0 = 0.f, s1 = 0.f, s2 = 0.f, s3 = 0.f;
  float cum = 1.f;
  float* yl = ylocal + ((size_t)bs * T_ + t0) * 32 + v;
  float* cd = cumd + (size_t)bs * T_ + t0;

#pragma unroll 4
  for (int t = 0; t < CL_; ++t) {
    const float* r = R + t * 128;
    const float4 k4 = *(const float4*)(r + n0);
    const float4 q4 = *(const float4*)(r + 32 + n0);
    const float vv = r[64 + v];
    const float d  = r[96];
    cum *= d;
    s0 = fmaf(d, s0, k4.x * vv);
    s1 = fmaf(d, s1, k4.y * vv);
    s2 = fmaf(d, s2, k4.z * vv);
    s3 = fmaf(d, s3, k4.w * vv);
    float p = fmaf(q4.x, s0, fmaf(q4.y, s1, fmaf(q4.z, s2, q4.w * s3)));
    p += __shfl_xor(p, 8); p += __shfl_xor(p, 16); p += __shfl_xor(p, 32);
    if (l < 8) yl[(size_t)t * 32] = p;
    if (threadIdx.x == 0) cd[t] = cum;
  }
  float* sl = Sloc + (((size_t)bs * NC_ + c) * 32 + n0) * 32 + v;
  sl[0] = s0; sl[32] = s1; sl[64] = s2; sl[96] = s3;
  if (threadIdx.x == 0) Pc[bs * NC_ + c] = cum;
}

// ---------------------------------------------------------------- chunked scan: pass 2
__global__ __launch_bounds__(256) void scan_pass2(const float* __restrict__ Sloc,
                                                  const float* __restrict__ Pc,
                                                  const float* __restrict__ S0,
                                                  float* __restrict__ Sin,
                                                  float* __restrict__ Sfin) {
  __shared__ float Ps[NC_];
  const int bs = blockIdx.x;
  if (threadIdx.x < NC_) Ps[threadIdx.x] = Pc[bs * NC_ + threadIdx.x];
  __syncthreads();

  const int e0 = threadIdx.x * 4;
  const float* gl = Sloc + (size_t)bs * NC_ * 1024 + e0;
  float4 S = *(const float4*)(S0 + (size_t)bs * 1024 + e0);
  float* sin_b = Sin + (size_t)bs * NC_ * 1024 + e0;
#pragma unroll 8
  for (int c = 0; c < NC_; ++c) {
    const float4 sl = *(const float4*)(gl + (size_t)c * 1024);
    *(float4*)(sin_b + (size_t)c * 1024) = S;
    const float pc = Ps[c];
    S.x = fmaf(pc, S.x, sl.x);
    S.y = fmaf(pc, S.y, sl.y);
    S.z = fmaf(pc, S.z, sl.z);
    S.w = fmaf(pc, S.w, sl.w);
  }
  *(float4*)(Sfin + (size_t)bs * 1024 + e0) = S;
}

// ---------------------------------------------------------------- chunked scan: pass 3
__global__ __launch_bounds__(256) void scan_pass3(const float* __restrict__ rec,
                                                  const float* __restrict__ ylocal,
                                                  const float* __restrict__ Sin,
                                                  const float* __restrict__ cumd,
                                                  __hip_bfloat16* __restrict__ Y) {
  __shared__ __align__(16) float Ss[1024];
  const int blk = blockIdx.x;
  const int bs = blk >> 5, c = blk & (NC_ - 1);
  const int b = bs >> 3, s = bs & 7;
  const int t0 = c * CL_;
  {
    const float* gs = Sin + ((size_t)bs * NC_ + c) * 1024;
    const int i = threadIdx.x;
    *(float4*)(Ss + (size_t)i * 4) = *(const float4*)(gs + (size_t)i * 4);
  }
  __syncthreads();

  const int w = threadIdx.x >> 6, l = threadIdx.x & 63;
  const int v = l & 31;
#pragma unroll
  for (int i = 0; i < 16; i += 2) {
    const int t = t0 + w * 16 + i + (l >> 5);
    const float* r = rec + ((size_t)bs * T_ + t) * 128;
    float p = 0.f;
#pragma unroll
    for (int nq = 0; nq < 8; ++nq) {
      const float4 q4 = *(const float4*)(r + 32 + nq * 4);
      p = fmaf(q4.x, Ss[(nq * 4 + 0) * 32 + v], p);
      p = fmaf(q4.y, Ss[(nq * 4 + 1) * 32 + v], p);
      p = fmaf(q4.z, Ss[(nq * 4 + 2) * 32 + v], p);
      p = fmaf(q4.w, Ss[(nq * 4 + 3) * 32 + v], p);
    }
    const float wt   = r[97];
    const float cdv  = cumd[(size_t)bs * T_ + t];
    const float yloc = ylocal[((size_t)bs * T_ + t) * 32 + v];
    const long m = (long)b * T_ + t;
    Y[(size_t)m * 256 + s * 32 + v] = __float2bfloat16(wt * (yloc + cdv * p));
  }
}

// ---------------------------------------------------------------- launch
extern "C" void kernel_launch(void* const* d_in, const int* in_sizes, int n_in,
                              void* d_out, int out_size, void* d_ws, size_t ws_size,
                              hipStream_t stream) {
  const float* x       = (const float*)d_in[0];
  const float* Wr      = (const float*)d_in[1];
  const float* Wq      = (const float*)d_in[2];
  const float* Wk      = (const float*)d_in[3];
  const float* Wv      = (const float*)d_in[4];
  const float* Wa      = (const float*)d_in[5];
  const float* A_log   = (const float*)d_in[6];
  const float* dt_bias = (const float*)d_in[7];
  const float* Wo      = (const float*)d_in[8];
  const float* S0      = (const float*)d_in[9];
  float* out = (float*)d_out;

  char* p = (char*)d_ws;
  auto alloc = [&](size_t bytes) -> void* {
    void* r = (void*)p; p += (bytes + 255) & ~(size_t)255; return r;
  };
  __hip_bfloat16* x_bf = (__hip_bfloat16*)alloc((size_t)NTOK * DIM_ * 2);
  __hip_bfloat16* Wg   = (__hip_bfloat16*)alloc((size_t)H_ * 96 * DIM_ * 2);
  float* WT   = (float*)alloc((size_t)DIM_ * RA_N * 4);
  float* RA   = (float*)alloc((size_t)NTOK * RA_N * 4);
  int*   idxb = (int*)  alloc((size_t)NPAIR * 4);
  float* rwb  = (float*)alloc((size_t)NPAIR * 4);
  float* decb = (float*)alloc((size_t)NPAIR * 4);
  int*   cnt  = (int*)  alloc(256);
  int*   wcnt = (int*)  alloc((size_t)NWIN * H_ * 4);
  int*   wbase= (int*)  alloc((size_t)NWIN * H_ * 4);
  int*   pairtok = (int*)alloc((size_t)H_ * NTOK * 4);
  float* recb = (float*)alloc((size_t)NSLOT * T_ * 128 * 4);
  __hip_bfloat16* Yb = (__hip_bfloat16*)alloc((size_t)NTOK * 256 * 2);
  __hip_bfloat16* B2 = (__hip_bfloat16*)alloc((size_t)DIM_ * 256 * 2);
  float* ylocal = (float*)alloc((size_t)NSLOT * T_ * 32 * 4);
  float* Slocb  = (float*)alloc((size_t)NSLOT * NC_ * 1024 * 4);
  float* Pcb    = (float*)alloc((size_t)NSLOT * NC_ * 4);
  float* Sinb   = (float*)alloc((size_t)NSLOT * NC_ * 1024 * 4);
  float* cumdb  = (float*)alloc((size_t)NSLOT * T_ * 4);

  cast_bf16<<<NTOK * DIM_ / 4 / 256, 256, 0, stream>>>(x, x_bf, NTOK * DIM_ / 4);
  build_wg<<<H_ * 96 * DIM_ / 4 / 256, 256, 0, stream>>>(Wq, Wk, Wv, Wg);
  build_b2<<<DIM_ * 256 / 256, 256, 0, stream>>>(Wo, B2);
  build_wt<<<DIM_ * RA_N / 256, 256, 0, stream>>>(Wr, Wa, WT);

  router_gemm<<<NTOK / 16, 256, 0, stream>>>(x, WT, RA);
  router_topk<<<NTOK / 4, 256, 0, stream>>>(RA, A_log, dt_bias, idxb, rwb, decb);

  hist_count<<<NWIN, 256, 0, stream>>>(idxb, wcnt);
  hist_scan<<<1, 64, 0, stream>>>(wcnt, wbase, cnt);
  hist_place<<<NWIN, 256, 0, stream>>>(idxb, wbase, pairtok);

  grouped_qkv<<<8192, 256, 0, stream>>>(
      (const short*)x_bf, (const short*)Wg, pairtok, cnt, rwb, decb, recb);

  scan_pass1<<<NSLOT * NC_, 256, 0, stream>>>(recb, ylocal, Slocb, Pcb, cumdb);
  scan_pass2<<<NSLOT, 256, 0, stream>>>(Slocb, Pcb, S0, Sinb, out + (size_t)NTOK * DIM_);
  scan_pass3<<<NSLOT * NC_, 256, 0, stream>>>(recb, ylocal, Sinb, cumdb, Yb);

  gemm_bt<false><<<dim3(DIM_ / 128, NTOK / 128), 256, 0, stream>>>(
      (const short*)Yb, (const short*)B2, out, NTOK, DIM_, 256);
}

// Round 9
// 267.019 us; speedup vs baseline: 1.1496x; 1.1496x over previous
//
#include <hip/hip_runtime.h>
#include <hip/hip_bf16.h>

typedef __attribute__((ext_vector_type(8))) short bf16x8;
typedef __attribute__((ext_vector_type(4))) float f32x4;

#define B_   4
#define T_   2048
#define DIM_ 1024
#define H_   64
#define NS_  32
#define K_   8
#define HV_  32
#define NTOK  (B_ * T_)   /* 8192 */
#define RA_N  128         /* router logits(64) | a(64) */
#define CL_   64          /* scan chunk length */
#define NC_   (T_ / CL_)  /* 32 chunks per slot */
#define NSLOT (B_ * K_)   /* 32 */
#define NPAIR (NTOK * K_) /* 65536 */
#define NWIN  32          /* bucketing windows (2048 pairs = 256 tokens each) */

// ---------------------------------------------------------------- helpers
__device__ __forceinline__ void gld_lds16(const void* g, void* s) {
  __builtin_amdgcn_global_load_lds(
      (const __attribute__((address_space(1))) void*)g,
      (__attribute__((address_space(3))) void*)s, 16, 0, 0);
}
__device__ __forceinline__ float silu_f(float x) { return x / (1.f + expf(-x)); }

// ---------------------------------------------------------------- prep
__global__ __launch_bounds__(256) void cast_bf16(const float* __restrict__ in,
                                                 __hip_bfloat16* __restrict__ out, int n4) {
  int i = blockIdx.x * 256 + threadIdx.x;
  if (i >= n4) return;
  const float4 v = *(const float4*)(in + (size_t)i * 4);
  union { short4 s4; __hip_bfloat16 h[4]; } u;
  u.h[0] = __float2bfloat16(v.x); u.h[1] = __float2bfloat16(v.y);
  u.h[2] = __float2bfloat16(v.z); u.h[3] = __float2bfloat16(v.w);
  *(short4*)(out + (size_t)i * 4) = u.s4;
}

// Wg[h][r][d], r<32: Wq[h*32+r], r<64: Wk[h*32+r-32], else Wv[h*32+r-64]  (bf16)
__global__ __launch_bounds__(256) void build_wg(const float* __restrict__ Wq,
                                                const float* __restrict__ Wk,
                                                const float* __restrict__ Wv,
                                                __hip_bfloat16* __restrict__ Wg) {
  int i = blockIdx.x * 256 + threadIdx.x;           // 6144*1024/4
  int row = i >> 8, c4 = (i & 255) * 4;
  int h = row / 96, r = row - h * 96;
  const float* src = (r < 32) ? (Wq + ((size_t)h * 32 + r) * 1024)
                   : (r < 64) ? (Wk + ((size_t)h * 32 + r - 32) * 1024)
                              : (Wv + ((size_t)h * 32 + r - 64) * 1024);
  const float4 v = *(const float4*)(src + c4);
  union { short4 s4; __hip_bfloat16 hh[4]; } u;
  u.hh[0] = __float2bfloat16(v.x); u.hh[1] = __float2bfloat16(v.y);
  u.hh[2] = __float2bfloat16(v.z); u.hh[3] = __float2bfloat16(v.w);
  *(short4*)(Wg + (size_t)row * 1024 + c4) = u.s4;
}

// B2[d][s*32+v] = Wo[d][v]  (slot-replicated Wo, bf16), 1024x256
__global__ __launch_bounds__(256) void build_b2(const float* __restrict__ Wo,
                                                __hip_bfloat16* __restrict__ B2) {
  int i = blockIdx.x * 256 + threadIdx.x;
  int d = i >> 8, c = i & 255;
  B2[i] = __float2bfloat16(Wo[d * 32 + (c & 31)]);
}

// WT[d][h] = (h<64 ? Wr : Wa)[h][d]   fp32, 1024x128
__global__ __launch_bounds__(256) void build_wt(const float* __restrict__ Wr,
                                                const float* __restrict__ Wa,
                                                float* __restrict__ WT) {
  int i = blockIdx.x * 256 + threadIdx.x;
  int d = i >> 7, h = i & 127;
  WT[i] = (h < 64) ? Wr[h * 1024 + d] : Wa[(h - 64) * 1024 + d];
}

// ---------------------------------------------------------------- router GEMM (fp32 exact, split-K x2)
__global__ __launch_bounds__(256) void router_gemm(const float* __restrict__ x,
                                                   const float* __restrict__ WT,
                                                   float* __restrict__ RA) {
  __shared__ float Lp[4][8][128];
  const int w = threadIdx.x >> 6, l = threadIdx.x & 63;
  const int t0 = blockIdx.x * 16 + (w >> 1) * 8;
  const int d0 = (w & 1) * 512;
  float a0[8] = {}, a1[8] = {};
  for (int d = d0; d < d0 + 512; d += 4) {
    float4 xv[8];
#pragma unroll
    for (int i = 0; i < 8; ++i) xv[i] = *(const float4*)(x + (size_t)(t0 + i) * DIM_ + d);
#pragma unroll
    for (int j = 0; j < 4; ++j) {
      const float w0 = WT[(d + j) * RA_N + l];
      const float w1 = WT[(d + j) * RA_N + 64 + l];
#pragma unroll
      for (int i = 0; i < 8; ++i) {
        const float xs = ((const float*)&xv[i])[j];
        a0[i] = fmaf(xs, w0, a0[i]);
        a1[i] = fmaf(xs, w1, a1[i]);
      }
    }
  }
#pragma unroll
  for (int i = 0; i < 8; ++i) { Lp[w][i][l] = a0[i]; Lp[w][i][64 + l] = a1[i]; }
  __syncthreads();
  for (int o = threadIdx.x; o < 2048; o += 256) {
    const int ti = o >> 7, cc = o & 127;
    const int wp = (ti >> 3) * 2;
    RA[(size_t)(blockIdx.x * 16 + ti) * RA_N + cc] = Lp[wp][ti & 7][cc] + Lp[wp + 1][ti & 7][cc];
  }
}

// ---------------------------------------------------------------- top-k + decay (1 wave / token)
__global__ __launch_bounds__(256) void router_topk(const float* __restrict__ RA,
                                                   const float* __restrict__ A_log,
                                                   const float* __restrict__ dt_bias,
                                                   int* __restrict__ idxb,
                                                   float* __restrict__ rwb,
                                                   float* __restrict__ decb) {
  const int w = threadIdx.x >> 6, l = threadIdx.x & 63;
  const int m = blockIdx.x * 4 + w;
  float zcur = RA[(size_t)m * RA_N + l];
  const int idx = l;
  float z0 = 0.f, myz = 0.f;
  int myh = 0;
#pragma unroll
  for (int i = 0; i < 8; ++i) {
    float v = zcur; int vi = idx;
#pragma unroll
    for (int off = 1; off < 64; off <<= 1) {
      float ov = __shfl_xor(v, off);
      int   oi = __shfl_xor(vi, off);
      if (ov > v || (ov == v && oi < vi)) { v = ov; vi = oi; }
    }
    if (i == 0) z0 = v;
    if (l == i) { myz = v; myh = vi; }
    if (idx == vi) zcur = -__builtin_inff();
  }
  float e = (l < 8) ? expf(myz - z0) : 0.f;
  float es = e;
  es += __shfl_xor(es, 1); es += __shfl_xor(es, 2); es += __shfl_xor(es, 4);
  if (l < 8) {
    const float a  = RA[(size_t)m * RA_N + 64 + myh];
    const float xb = a + dt_bias[myh];
    const float dt = (xb > 20.f) ? xb : log1pf(expf(xb));
    idxb[m * 8 + l] = myh;
    rwb [m * 8 + l] = e / es;
    decb[m * 8 + l] = expf(-expf(A_log[myh]) * dt);
  }
}

// ---------------------------------------------------------------- window-sorted head bucketing
// pairtok[h] ordered by 256-token window; chunk c of every head covers the
// same ~512-token span, so co-resident blocks share their x working set.
__global__ __launch_bounds__(256) void hist_count(const int* __restrict__ idxb,
                                                  int* __restrict__ wcnt) {
  __shared__ int lh[H_];
  const int tid = threadIdx.x;
  if (tid < H_) lh[tid] = 0;
  __syncthreads();
  const int base = blockIdx.x * (NPAIR / NWIN);
#pragma unroll
  for (int j = 0; j < 8; ++j) atomicAdd(&lh[idxb[base + j * 256 + tid]], 1);
  __syncthreads();
  if (tid < H_) wcnt[blockIdx.x * H_ + tid] = lh[tid];
}

__global__ void hist_scan(const int* __restrict__ wcnt,
                          int* __restrict__ wbase, int* __restrict__ cnt) {
  const int h = threadIdx.x;
  if (h >= H_) return;
  int run = 0;
  for (int w = 0; w < NWIN; ++w) { wbase[w * H_ + h] = run; run += wcnt[w * H_ + h]; }
  cnt[h] = run;
}

__global__ __launch_bounds__(256) void hist_place(const int* __restrict__ idxb,
                                                  const int* __restrict__ wbase,
                                                  int* __restrict__ pairtok) {
  __shared__ int lcur[H_];
  const int tid = threadIdx.x;
  if (tid < H_) lcur[tid] = wbase[blockIdx.x * H_ + tid];
  __syncthreads();
  const int base = blockIdx.x * (NPAIR / NWIN);
#pragma unroll
  for (int j = 0; j < 8; ++j) {
    const int pid = base + j * 256 + tid;
    const int h = idxb[pid];
    const int pos = atomicAdd(&lcur[h], 1);
    pairtok[h * NTOK + pos] = pid;
  }
}

// ---------------------------------------------------------------- grouped QKV projection
// Head-affine XCD mapping (v7: weights L2-resident per XCD) + window-sorted
// pairtok (co-resident chunks share a ~3MB x window -> x also L2-resident).
// sched_group_barrier pins per-step emission: 8 VMEM reads (next step's
// fragments) BEFORE the 12 MFMAs -> ~8 loads in flight per wave.
__global__ __launch_bounds__(256, 4) void grouped_qkv(const short* __restrict__ x_bf,
                                                      const short* __restrict__ Wg,
                                                      const int* __restrict__ pairtok,
                                                      const int* __restrict__ cnt,
                                                      const float* __restrict__ rwb,
                                                      const float* __restrict__ decb,
                                                      float* __restrict__ rec) {
  const int bid = blockIdx.x;
  const int h = (bid & 7) | (((bid >> 3) & 7) << 3);  // bid%8 == h%8 (XCD affinity)
  const int c = bid >> 6;                             // 0..127 chunk of 64 rows
  const int n = cnt[h];
  if (c * 64 >= n) return;
  __shared__ int prs[64];
  __shared__ __align__(16) float red[64 * 97];        // ~24.8 KB reduction buffer
  if (threadIdx.x < 64) {
    const int ri = c * 64 + threadIdx.x;
    prs[threadIdx.x] = (ri < n) ? pairtok[h * NTOK + ri] : -1;
  }
  __syncthreads();

  const int w = threadIdx.x >> 6, l = threadIdx.x & 63;
  const int wr = w >> 1, wk = w & 1;                  // row-group, K-half
  const int lr = l & 15, lk = l >> 4;
  const int rowbase = wr * 32;
  const int fallback = prs[0] >> 3;
  const int p0 = prs[rowbase + lr], p1 = prs[rowbase + 16 + lr];
  const long tok0 = (p0 >= 0) ? (long)(p0 >> 3) : fallback;
  const long tok1 = (p1 >= 0) ? (long)(p1 >> 3) : fallback;
  const short* a0p = x_bf + tok0 * DIM_ + wk * 512 + lk * 8;
  const short* a1p = x_bf + tok1 * DIM_ + wk * 512 + lk * 8;
  const short* bp  = Wg + ((size_t)h * 96 + lr) * DIM_ + wk * 512 + lk * 8;

  f32x4 acc[2][6] = {};
  bf16x8 a0c = *(const bf16x8*)a0p;
  bf16x8 a1c = *(const bf16x8*)a1p;
  bf16x8 bc[6];
#pragma unroll
  for (int j = 0; j < 6; ++j) bc[j] = *(const bf16x8*)(bp + (size_t)j * 16 * DIM_);

  for (int k0 = 32; k0 < 512; k0 += 32) {
    const bf16x8 a0n = *(const bf16x8*)(a0p + k0);
    const bf16x8 a1n = *(const bf16x8*)(a1p + k0);
    bf16x8 bn[6];
#pragma unroll
    for (int j = 0; j < 6; ++j) bn[j] = *(const bf16x8*)(bp + (size_t)j * 16 * DIM_ + k0);
#pragma unroll
    for (int j = 0; j < 6; ++j) {
      acc[0][j] = __builtin_amdgcn_mfma_f32_16x16x32_bf16(a0c, bc[j], acc[0][j], 0, 0, 0);
      acc[1][j] = __builtin_amdgcn_mfma_f32_16x16x32_bf16(a1c, bc[j], acc[1][j], 0, 0, 0);
    }
    // pin schedule: 8 VMEM_READ (0x20) for step k+1 emitted before the
    // 12 MFMA (0x8) of step k  -> loads stay in flight across the MFMAs.
    __builtin_amdgcn_sched_group_barrier(0x20, 8, 0);
    __builtin_amdgcn_sched_group_barrier(0x8, 12, 0);
    a0c = a0n; a1c = a1n;
#pragma unroll
    for (int j = 0; j < 6; ++j) bc[j] = bn[j];
  }
#pragma unroll
  for (int j = 0; j < 6; ++j) {                       // tail K-step
    acc[0][j] = __builtin_amdgcn_mfma_f32_16x16x32_bf16(a0c, bc[j], acc[0][j], 0, 0, 0);
    acc[1][j] = __builtin_amdgcn_mfma_f32_16x16x32_bf16(a1c, bc[j], acc[1][j], 0, 0, 0);
  }

  // cross-K reduction: wk=1 dumps, wk=0 accumulates
  if (wk) {
#pragma unroll
    for (int i = 0; i < 2; ++i)
#pragma unroll
      for (int j = 0; j < 6; ++j)
#pragma unroll
        for (int r = 0; r < 4; ++r)
          red[(rowbase + i * 16 + lk * 4 + r) * 97 + j * 16 + lr] = acc[i][j][r];
  }
  __syncthreads();
  if (wk == 0) {
#pragma unroll
    for (int i = 0; i < 2; ++i)
#pragma unroll
      for (int j = 0; j < 6; ++j)
#pragma unroll
        for (int r = 0; r < 4; ++r)
          acc[i][j][r] += red[(rowbase + i * 16 + lk * 4 + r) * 97 + j * 16 + lr];

    // epilogue: cols j0,j1=q j2,j3=k j4,j5=v ; row = rowbase + i*16 + lk*4 + r
#pragma unroll
    for (int i = 0; i < 2; ++i) {
#pragma unroll
      for (int r = 0; r < 4; ++r) {
        const int row = rowbase + i * 16 + lk * 4 + r;
        const int p = prs[row];
        float q0v = silu_f(acc[i][0][r]), q1v = silu_f(acc[i][1][r]);
        float k0v = silu_f(acc[i][2][r]), k1v = silu_f(acc[i][3][r]);
        float v0 = silu_f(acc[i][4][r]), v1 = silu_f(acc[i][5][r]);
        float ssq = q0v * q0v + q1v * q1v;
        float ssk = k0v * k0v + k1v * k1v;
        ssq += __shfl_xor(ssq, 1); ssq += __shfl_xor(ssq, 2);
        ssq += __shfl_xor(ssq, 4); ssq += __shfl_xor(ssq, 8);
        ssk += __shfl_xor(ssk, 1); ssk += __shfl_xor(ssk, 2);
        ssk += __shfl_xor(ssk, 4); ssk += __shfl_xor(ssk, 8);
        const float rq = rsqrtf(ssq + 1e-6f), rk = rsqrtf(ssk + 1e-6f);
        if (p >= 0) {
          const int m = p >> 3, s = p & 7;
          const int b = m >> 11, t = m & (T_ - 1);
          float* rb = rec + (((size_t)(b * 8 + s)) * T_ + t) * 128;
          rb[lr]      = k0v * rk;
          rb[16 + lr] = k1v * rk;
          rb[32 + lr] = q0v * rq;
          rb[48 + lr] = q1v * rq;
          rb[64 + lr] = v0;
          rb[80 + lr] = v1;
          if (lr == 0) { rb[96] = decb[p]; rb[97] = rwb[p]; }
        }
      }
    }
  }
}

// ---------------------------------------------------------------- bf16 MFMA GEMM, C = A * B^T (final proj)
template <bool OUT_BF16>
__global__ __launch_bounds__(256) void gemm_bt(const short* __restrict__ A,
                                               const short* __restrict__ Bm,
                                               void* __restrict__ Cout,
                                               int M, int N, int K) {
  __shared__ __align__(16) short As[2][128 * 32];
  __shared__ __align__(16) short Bs[2][128 * 32];
  const int tid = threadIdx.x;
  const int w = tid >> 6, l = tid & 63;
  const int m0 = blockIdx.y * 128, n0 = blockIdx.x * 128;
  const int wr = (w >> 1) * 64, wc = (w & 1) * 64;
  const int rsub = l >> 2, csub = (l & 3) * 8;
  const int lr = l & 15, lk = l >> 4;
  f32x4 acc[4][4] = {};

  auto STAGE = [&](int buf, int k0) {
#pragma unroll
    for (int j = 0; j < 2; ++j) {
      const int ra = w * 32 + j * 16;
      gld_lds16(A  + (size_t)(m0 + ra + rsub) * K + k0 + csub, As[buf] + ra * 32);
      gld_lds16(Bm + (size_t)(n0 + ra + rsub) * K + k0 + csub, Bs[buf] + ra * 32);
    }
  };

  STAGE(0, 0);
  __syncthreads();
  int cur = 0;
  for (int k0 = 0; k0 < K; k0 += 32) {
    if (k0 + 32 < K) STAGE(cur ^ 1, k0 + 32);
    bf16x8 af[4], bfr[4];
#pragma unroll
    for (int i = 0; i < 4; ++i) af[i]  = *(const bf16x8*)(As[cur] + (wr + i * 16 + lr) * 32 + lk * 8);
#pragma unroll
    for (int j = 0; j < 4; ++j) bfr[j] = *(const bf16x8*)(Bs[cur] + (wc + j * 16 + lr) * 32 + lk * 8);
#pragma unroll
    for (int i = 0; i < 4; ++i)
#pragma unroll
      for (int j = 0; j < 4; ++j)
        acc[i][j] = __builtin_amdgcn_mfma_f32_16x16x32_bf16(af[i], bfr[j], acc[i][j], 0, 0, 0);
    __syncthreads();
    cur ^= 1;
  }
#pragma unroll
  for (int i = 0; i < 4; ++i)
#pragma unroll
    for (int j = 0; j < 4; ++j) {
      const size_t row0 = (size_t)m0 + wr + i * 16 + lk * 4;
      const size_t col  = (size_t)n0 + wc + j * 16 + lr;
#pragma unroll
      for (int r = 0; r < 4; ++r) {
        if constexpr (OUT_BF16)
          ((__hip_bfloat16*)Cout)[(row0 + r) * N + col] = __float2bfloat16(acc[i][j][r]);
        else
          ((float*)Cout)[(row0 + r) * N + col] = acc[i][j][r];
      }
    }
}

// ---------------------------------------------------------------- chunked scan: pass 1
__global__ __launch_bounds__(256) void scan_pass1(const float* __restrict__ rec,
                                                  float* __restrict__ ylocal,
                                                  float* __restrict__ Sloc,
                                                  float* __restrict__ Pc,
                                                  float* __restrict__ cumd) {
  __shared__ __align__(16) float R[CL_ * 128];   // 32 KB
  const int blk = blockIdx.x;
  const int bs = blk >> 5, c = blk & (NC_ - 1);
  const int t0 = c * CL_;
  const float* g = rec + ((size_t)bs * T_ + t0) * 128;
  for (int i = threadIdx.x; i < CL_ * 32; i += 256)
    *(float4*)(R + (size_t)i * 4) = *(const float4*)(g + (size_t)i * 4);
  __syncthreads();

  const int w = threadIdx.x >> 6, l = threadIdx.x & 63;
  const int v = w * 8 + (l & 7);
  const int n0 = (l >> 3) * 4;
  float s0 = 0.f, s1 = 0.f, s2 = 0.f, s3 = 0.f;
  float cum = 1.f;
  float* yl = ylocal + ((size_t)bs * T_ + t0) * 32 + v;
  float* cd = cumd + (size_t)bs * T_ + t0;

#pragma unroll 4
  for (int t = 0; t < CL_; ++t) {
    const float* r = R + t * 128;
    const float4 k4 = *(const float4*)(r + n0);
    const float4 q4 = *(const float4*)(r + 32 + n0);
    const float vv = r[64 + v];
    const float d  = r[96];
    cum *= d;
    s0 = fmaf(d, s0, k4.x * vv);
    s1 = fmaf(d, s1, k4.y * vv);
    s2 = fmaf(d, s2, k4.z * vv);
    s3 = fmaf(d, s3, k4.w * vv);
    float p = fmaf(q4.x, s0, fmaf(q4.y, s1, fmaf(q4.z, s2, q4.w * s3)));
    p += __shfl_xor(p, 8); p += __shfl_xor(p, 16); p += __shfl_xor(p, 32);
    if (l < 8) yl[(size_t)t * 32] = p;
    if (threadIdx.x == 0) cd[t] = cum;
  }
  float* sl = Sloc + (((size_t)bs * NC_ + c) * 32 + n0) * 32 + v;
  sl[0] = s0; sl[32] = s1; sl[64] = s2; sl[96] = s3;
  if (threadIdx.x == 0) Pc[bs * NC_ + c] = cum;
}

// ---------------------------------------------------------------- chunked scan: pass 2
__global__ __launch_bounds__(256) void scan_pass2(const float* __restrict__ Sloc,
                                                  const float* __restrict__ Pc,
                                                  const float* __restrict__ S0,
                                                  float* __restrict__ Sin,
                                                  float* __restrict__ Sfin) {
  __shared__ float Ps[NC_];
  const int bs = blockIdx.x;
  if (threadIdx.x < NC_) Ps[threadIdx.x] = Pc[bs * NC_ + threadIdx.x];
  __syncthreads();

  const int e0 = threadIdx.x * 4;
  const float* gl = Sloc + (size_t)bs * NC_ * 1024 + e0;
  float4 S = *(const float4*)(S0 + (size_t)bs * 1024 + e0);
  float* sin_b = Sin + (size_t)bs * NC_ * 1024 + e0;
#pragma unroll 8
  for (int c = 0; c < NC_; ++c) {
    const float4 sl = *(const float4*)(gl + (size_t)c * 1024);
    *(float4*)(sin_b + (size_t)c * 1024) = S;
    const float pc = Ps[c];
    S.x = fmaf(pc, S.x, sl.x);
    S.y = fmaf(pc, S.y, sl.y);
    S.z = fmaf(pc, S.z, sl.z);
    S.w = fmaf(pc, S.w, sl.w);
  }
  *(float4*)(Sfin + (size_t)bs * 1024 + e0) = S;
}

// ---------------------------------------------------------------- chunked scan: pass 3
__global__ __launch_bounds__(256) void scan_pass3(const float* __restrict__ rec,
                                                  const float* __restrict__ ylocal,
                                                  const float* __restrict__ Sin,
                                                  const float* __restrict__ cumd,
                                                  __hip_bfloat16* __restrict__ Y) {
  __shared__ __align__(16) float Ss[1024];
  const int blk = blockIdx.x;
  const int bs = blk >> 5, c = blk & (NC_ - 1);
  const int b = bs >> 3, s = bs & 7;
  const int t0 = c * CL_;
  {
    const float* gs = Sin + ((size_t)bs * NC_ + c) * 1024;
    const int i = threadIdx.x;
    *(float4*)(Ss + (size_t)i * 4) = *(const float4*)(gs + (size_t)i * 4);
  }
  __syncthreads();

  const int w = threadIdx.x >> 6, l = threadIdx.x & 63;
  const int v = l & 31;
#pragma unroll
  for (int i = 0; i < 16; i += 2) {
    const int t = t0 + w * 16 + i + (l >> 5);
    const float* r = rec + ((size_t)bs * T_ + t) * 128;
    float p = 0.f;
#pragma unroll
    for (int nq = 0; nq < 8; ++nq) {
      const float4 q4 = *(const float4*)(r + 32 + nq * 4);
      p = fmaf(q4.x, Ss[(nq * 4 + 0) * 32 + v], p);
      p = fmaf(q4.y, Ss[(nq * 4 + 1) * 32 + v], p);
      p = fmaf(q4.z, Ss[(nq * 4 + 2) * 32 + v], p);
      p = fmaf(q4.w, Ss[(nq * 4 + 3) * 32 + v], p);
    }
    const float wt   = r[97];
    const float cdv  = cumd[(size_t)bs * T_ + t];
    const float yloc = ylocal[((size_t)bs * T_ + t) * 32 + v];
    const long m = (long)b * T_ + t;
    Y[(size_t)m * 256 + s * 32 + v] = __float2bfloat16(wt * (yloc + cdv * p));
  }
}

// ---------------------------------------------------------------- launch
extern "C" void kernel_launch(void* const* d_in, const int* in_sizes, int n_in,
                              void* d_out, int out_size, void* d_ws, size_t ws_size,
                              hipStream_t stream) {
  const float* x       = (const float*)d_in[0];
  const float* Wr      = (const float*)d_in[1];
  const float* Wq      = (const float*)d_in[2];
  const float* Wk      = (const float*)d_in[3];
  const float* Wv      = (const float*)d_in[4];
  const float* Wa      = (const float*)d_in[5];
  const float* A_log   = (const float*)d_in[6];
  const float* dt_bias = (const float*)d_in[7];
  const float* Wo      = (const float*)d_in[8];
  const float* S0      = (const float*)d_in[9];
  float* out = (float*)d_out;

  char* p = (char*)d_ws;
  auto alloc = [&](size_t bytes) -> void* {
    void* r = (void*)p; p += (bytes + 255) & ~(size_t)255; return r;
  };
  __hip_bfloat16* x_bf = (__hip_bfloat16*)alloc((size_t)NTOK * DIM_ * 2);
  __hip_bfloat16* Wg   = (__hip_bfloat16*)alloc((size_t)H_ * 96 * DIM_ * 2);
  float* WT   = (float*)alloc((size_t)DIM_ * RA_N * 4);
  float* RA   = (float*)alloc((size_t)NTOK * RA_N * 4);
  int*   idxb = (int*)  alloc((size_t)NPAIR * 4);
  float* rwb  = (float*)alloc((size_t)NPAIR * 4);
  float* decb = (float*)alloc((size_t)NPAIR * 4);
  int*   cnt  = (int*)  alloc(256);
  int*   wcnt = (int*)  alloc((size_t)NWIN * H_ * 4);
  int*   wbase= (int*)  alloc((size_t)NWIN * H_ * 4);
  int*   pairtok = (int*)alloc((size_t)H_ * NTOK * 4);
  float* recb = (float*)alloc((size_t)NSLOT * T_ * 128 * 4);
  __hip_bfloat16* Yb = (__hip_bfloat16*)alloc((size_t)NTOK * 256 * 2);
  __hip_bfloat16* B2 = (__hip_bfloat16*)alloc((size_t)DIM_ * 256 * 2);
  float* ylocal = (float*)alloc((size_t)NSLOT * T_ * 32 * 4);
  float* Slocb  = (float*)alloc((size_t)NSLOT * NC_ * 1024 * 4);
  float* Pcb    = (float*)alloc((size_t)NSLOT * NC_ * 4);
  float* Sinb   = (float*)alloc((size_t)NSLOT * NC_ * 1024 * 4);
  float* cumdb  = (float*)alloc((size_t)NSLOT * T_ * 4);

  cast_bf16<<<NTOK * DIM_ / 4 / 256, 256, 0, stream>>>(x, x_bf, NTOK * DIM_ / 4);
  build_wg<<<H_ * 96 * DIM_ / 4 / 256, 256, 0, stream>>>(Wq, Wk, Wv, Wg);
  build_b2<<<DIM_ * 256 / 256, 256, 0, stream>>>(Wo, B2);
  build_wt<<<DIM_ * RA_N / 256, 256, 0, stream>>>(Wr, Wa, WT);

  router_gemm<<<NTOK / 16, 256, 0, stream>>>(x, WT, RA);
  router_topk<<<NTOK / 4, 256, 0, stream>>>(RA, A_log, dt_bias, idxb, rwb, decb);

  hist_count<<<NWIN, 256, 0, stream>>>(idxb, wcnt);
  hist_scan<<<1, 64, 0, stream>>>(wcnt, wbase, cnt);
  hist_place<<<NWIN, 256, 0, stream>>>(idxb, wbase, pairtok);

  grouped_qkv<<<8192, 256, 0, stream>>>(
      (const short*)x_bf, (const short*)Wg, pairtok, cnt, rwb, decb, recb);

  scan_pass1<<<NSLOT * NC_, 256, 0, stream>>>(recb, ylocal, Slocb, Pcb, cumdb);
  scan_pass2<<<NSLOT, 256, 0, stream>>>(Slocb, Pcb, S0, Sinb, out + (size_t)NTOK * DIM_);
  scan_pass3<<<NSLOT * NC_, 256, 0, stream>>>(recb, ylocal, Sinb, cumdb, Yb);

  gemm_bt<false><<<dim3(DIM_ / 128, NTOK / 128), 256, 0, stream>>>(
      (const short*)Yb, (const short*)B2, out, NTOK, DIM_, 256);
}

// Round 10
// 257.283 us; speedup vs baseline: 1.1931x; 1.0378x over previous
//
#include <hip/hip_runtime.h>
#include <hip/hip_bf16.h>

typedef __attribute__((ext_vector_type(8))) short bf16x8;
typedef __attribute__((ext_vector_type(4))) float f32x4;

#define B_   4
#define T_   2048
#define DIM_ 1024
#define H_   64
#define NS_  32
#define K_   8
#define HV_  32
#define NTOK  (B_ * T_)   /* 8192 */
#define RA_N  128         /* router logits(64) | a(64) */
#define CL_   64          /* scan chunk length */
#define NC_   (T_ / CL_)  /* 32 chunks per slot */
#define NSLOT (B_ * K_)   /* 32 */
#define NPAIR (NTOK * K_) /* 65536 */

// ---------------------------------------------------------------- helpers
__device__ __forceinline__ void gld_lds16(const void* g, void* s) {
  __builtin_amdgcn_global_load_lds(
      (const __attribute__((address_space(1))) void*)g,
      (__attribute__((address_space(3))) void*)s, 16, 0, 0);
}
__device__ __forceinline__ float silu_f(float x) { return x / (1.f + expf(-x)); }

// ---------------------------------------------------------------- prep
__global__ __launch_bounds__(256) void cast_bf16(const float* __restrict__ in,
                                                 __hip_bfloat16* __restrict__ out, int n4) {
  int i = blockIdx.x * 256 + threadIdx.x;
  if (i >= n4) return;
  const float4 v = *(const float4*)(in + (size_t)i * 4);
  union { short4 s4; __hip_bfloat16 h[4]; } u;
  u.h[0] = __float2bfloat16(v.x); u.h[1] = __float2bfloat16(v.y);
  u.h[2] = __float2bfloat16(v.z); u.h[3] = __float2bfloat16(v.w);
  *(short4*)(out + (size_t)i * 4) = u.s4;
}

// Wg[h][r][d], r<32: Wq[h*32+r], r<64: Wk[h*32+r-32], else Wv[h*32+r-64]  (bf16)
__global__ __launch_bounds__(256) void build_wg(const float* __restrict__ Wq,
                                                const float* __restrict__ Wk,
                                                const float* __restrict__ Wv,
                                                __hip_bfloat16* __restrict__ Wg) {
  int i = blockIdx.x * 256 + threadIdx.x;           // 6144*1024/4
  int row = i >> 8, c4 = (i & 255) * 4;
  int h = row / 96, r = row - h * 96;
  const float* src = (r < 32) ? (Wq + ((size_t)h * 32 + r) * 1024)
                   : (r < 64) ? (Wk + ((size_t)h * 32 + r - 32) * 1024)
                              : (Wv + ((size_t)h * 32 + r - 64) * 1024);
  const float4 v = *(const float4*)(src + c4);
  union { short4 s4; __hip_bfloat16 hh[4]; } u;
  u.hh[0] = __float2bfloat16(v.x); u.hh[1] = __float2bfloat16(v.y);
  u.hh[2] = __float2bfloat16(v.z); u.hh[3] = __float2bfloat16(v.w);
  *(short4*)(Wg + (size_t)row * 1024 + c4) = u.s4;
}

// B2[d][s*32+v] = Wo[d][v]  (slot-replicated Wo, bf16), 1024x256
__global__ __launch_bounds__(256) void build_b2(const float* __restrict__ Wo,
                                                __hip_bfloat16* __restrict__ B2) {
  int i = blockIdx.x * 256 + threadIdx.x;
  int d = i >> 8, c = i & 255;
  B2[i] = __float2bfloat16(Wo[d * 32 + (c & 31)]);
}

// WT[d][h] = (h<64 ? Wr : Wa)[h][d]   fp32, 1024x128
__global__ __launch_bounds__(256) void build_wt(const float* __restrict__ Wr,
                                                const float* __restrict__ Wa,
                                                float* __restrict__ WT) {
  int i = blockIdx.x * 256 + threadIdx.x;
  int d = i >> 7, h = i & 127;
  WT[i] = (h < 64) ? Wr[h * 1024 + d] : Wa[(h - 64) * 1024 + d];
}

// ---------------------------------------------------------------- router GEMM (fp32 exact, split-K x2)
__global__ __launch_bounds__(256) void router_gemm(const float* __restrict__ x,
                                                   const float* __restrict__ WT,
                                                   float* __restrict__ RA) {
  __shared__ float Lp[4][8][128];
  const int w = threadIdx.x >> 6, l = threadIdx.x & 63;
  const int t0 = blockIdx.x * 16 + (w >> 1) * 8;
  const int d0 = (w & 1) * 512;
  float a0[8] = {}, a1[8] = {};
  for (int d = d0; d < d0 + 512; d += 4) {
    float4 xv[8];
#pragma unroll
    for (int i = 0; i < 8; ++i) xv[i] = *(const float4*)(x + (size_t)(t0 + i) * DIM_ + d);
#pragma unroll
    for (int j = 0; j < 4; ++j) {
      const float w0 = WT[(d + j) * RA_N + l];
      const float w1 = WT[(d + j) * RA_N + 64 + l];
#pragma unroll
      for (int i = 0; i < 8; ++i) {
        const float xs = ((const float*)&xv[i])[j];
        a0[i] = fmaf(xs, w0, a0[i]);
        a1[i] = fmaf(xs, w1, a1[i]);
      }
    }
  }
#pragma unroll
  for (int i = 0; i < 8; ++i) { Lp[w][i][l] = a0[i]; Lp[w][i][64 + l] = a1[i]; }
  __syncthreads();
  for (int o = threadIdx.x; o < 2048; o += 256) {
    const int ti = o >> 7, cc = o & 127;
    const int wp = (ti >> 3) * 2;
    RA[(size_t)(blockIdx.x * 16 + ti) * RA_N + cc] = Lp[wp][ti & 7][cc] + Lp[wp + 1][ti & 7][cc];
  }
}

// ---------------------------------------------------------------- top-k + decay (1 wave / token)
__global__ __launch_bounds__(256) void router_topk(const float* __restrict__ RA,
                                                   const float* __restrict__ A_log,
                                                   const float* __restrict__ dt_bias,
                                                   int* __restrict__ idxb,
                                                   float* __restrict__ rwb,
                                                   float* __restrict__ decb) {
  const int w = threadIdx.x >> 6, l = threadIdx.x & 63;
  const int m = blockIdx.x * 4 + w;
  float zcur = RA[(size_t)m * RA_N + l];
  const int idx = l;
  float z0 = 0.f, myz = 0.f;
  int myh = 0;
#pragma unroll
  for (int i = 0; i < 8; ++i) {
    float v = zcur; int vi = idx;
#pragma unroll
    for (int off = 1; off < 64; off <<= 1) {
      float ov = __shfl_xor(v, off);
      int   oi = __shfl_xor(vi, off);
      if (ov > v || (ov == v && oi < vi)) { v = ov; vi = oi; }
    }
    if (i == 0) z0 = v;
    if (l == i) { myz = v; myh = vi; }
    if (idx == vi) zcur = -__builtin_inff();
  }
  float e = (l < 8) ? expf(myz - z0) : 0.f;
  float es = e;
  es += __shfl_xor(es, 1); es += __shfl_xor(es, 2); es += __shfl_xor(es, 4);
  if (l < 8) {
    const float a  = RA[(size_t)m * RA_N + 64 + myh];
    const float xb = a + dt_bias[myh];
    const float dt = (xb > 20.f) ? xb : log1pf(expf(xb));
    idxb[m * 8 + l] = myh;
    rwb [m * 8 + l] = e / es;
    decb[m * 8 + l] = expf(-expf(A_log[myh]) * dt);
  }
}

// ---------------------------------------------------------------- head bucketing
__global__ void zero_cnt(int* __restrict__ cnt) {
  if (threadIdx.x < H_) cnt[threadIdx.x] = 0;
}

// LDS-aggregated bucketing (R7): 32 blocks x 2048 pairs, per-block LDS
// histogram, one global atomicAdd per (head, block). Bucket-internal order
// nondeterministic; rec rows keyed by pair id -> d_out deterministic.
__global__ __launch_bounds__(256) void hist_bucket(const int* __restrict__ idxb,
                                                   int* __restrict__ cnt,
                                                   int* __restrict__ pairtok) {
  __shared__ int lh[H_];
  __shared__ int lcur[H_];
  const int tid = threadIdx.x;
  if (tid < H_) lh[tid] = 0;
  __syncthreads();
  const int base = blockIdx.x * (NPAIR / 32);   // 2048 pairs/block
  int hs[8];
#pragma unroll
  for (int j = 0; j < 8; ++j) {
    hs[j] = idxb[base + j * 256 + tid];
    atomicAdd(&lh[hs[j]], 1);
  }
  __syncthreads();
  if (tid < H_) lcur[tid] = atomicAdd(&cnt[tid], lh[tid]);
  __syncthreads();
#pragma unroll
  for (int j = 0; j < 8; ++j) {
    const int pos = atomicAdd(&lcur[hs[j]], 1);
    pairtok[hs[j] * NTOK + pos] = base + j * 256 + tid;
  }
}

// ---------------------------------------------------------------- grouped QKV projection
// R7 structure (64-row blocks, 4 waves = 2 row-groups x 2 K-halves, head-
// affine XCD map) + 2-deep register prefetch: 4 named fragment generations,
// 16 loads in flight per wave. launch_bounds(256,2) gives the allocator
// 256-VGPR headroom so the pipeline actually materializes (R9 evidence:
// at (256,4) the compiler collapsed it to 64 VGPRs).
__global__ __launch_bounds__(256, 2) void grouped_qkv(const short* __restrict__ x_bf,
                                                      const short* __restrict__ Wg,
                                                      const int* __restrict__ pairtok,
                                                      const int* __restrict__ cnt,
                                                      const float* __restrict__ rwb,
                                                      const float* __restrict__ decb,
                                                      float* __restrict__ rec) {
  const int bid = blockIdx.x;
  const int h = (bid & 7) | (((bid >> 3) & 7) << 3);  // bid%8 == h%8 (XCD affinity)
  const int c = bid >> 6;                             // 0..127 chunk of 64 rows
  const int n = cnt[h];
  if (c * 64 >= n) return;
  __shared__ int prs[64];
  __shared__ __align__(16) float red[64 * 97];        // ~24.8 KB reduction buffer
  if (threadIdx.x < 64) {
    const int ri = c * 64 + threadIdx.x;
    prs[threadIdx.x] = (ri < n) ? pairtok[h * NTOK + ri] : -1;
  }
  __syncthreads();

  const int w = threadIdx.x >> 6, l = threadIdx.x & 63;
  const int wr = w >> 1, wk = w & 1;                  // row-group, K-half
  const int lr = l & 15, lk = l >> 4;
  const int rowbase = wr * 32;
  const int fallback = prs[0] >> 3;
  const int p0 = prs[rowbase + lr], p1 = prs[rowbase + 16 + lr];
  const long tok0 = (p0 >= 0) ? (long)(p0 >> 3) : fallback;
  const long tok1 = (p1 >= 0) ? (long)(p1 >> 3) : fallback;
  const short* a0p = x_bf + tok0 * DIM_ + wk * 512 + lk * 8;
  const short* a1p = x_bf + tok1 * DIM_ + wk * 512 + lk * 8;
  const short* bp  = Wg + ((size_t)h * 96 + lr) * DIM_ + wk * 512 + lk * 8;

  f32x4 acc[2][6] = {};

  // ---- 2-deep pipeline: generations A (step k) and Bv (step k+32)
  bf16x8 A0a = *(const bf16x8*)(a0p);
  bf16x8 A1a = *(const bf16x8*)(a1p);
  bf16x8 Ba[6];
#pragma unroll
  for (int j = 0; j < 6; ++j) Ba[j] = *(const bf16x8*)(bp + (size_t)j * 16 * DIM_);
  bf16x8 A0b = *(const bf16x8*)(a0p + 32);
  bf16x8 A1b = *(const bf16x8*)(a1p + 32);
  bf16x8 Bb[6];
#pragma unroll
  for (int j = 0; j < 6; ++j) Bb[j] = *(const bf16x8*)(bp + (size_t)j * 16 * DIM_ + 32);

  // 7 iterations x 2 steps (k = 0..448), prefetching k+64 / k+96 (max 480 < 512)
  for (int k0 = 0; k0 < 416; k0 += 64) {
    bf16x8 nA0a = *(const bf16x8*)(a0p + k0 + 64);
    bf16x8 nA1a = *(const bf16x8*)(a1p + k0 + 64);
    bf16x8 nBa[6];
#pragma unroll
    for (int j = 0; j < 6; ++j) nBa[j] = *(const bf16x8*)(bp + (size_t)j * 16 * DIM_ + k0 + 64);
#pragma unroll
    for (int j = 0; j < 6; ++j) {
      acc[0][j] = __builtin_amdgcn_mfma_f32_16x16x32_bf16(A0a, Ba[j], acc[0][j], 0, 0, 0);
      acc[1][j] = __builtin_amdgcn_mfma_f32_16x16x32_bf16(A1a, Ba[j], acc[1][j], 0, 0, 0);
    }
    bf16x8 nA0b = *(const bf16x8*)(a0p + k0 + 96);
    bf16x8 nA1b = *(const bf16x8*)(a1p + k0 + 96);
    bf16x8 nBb[6];
#pragma unroll
    for (int j = 0; j < 6; ++j) nBb[j] = *(const bf16x8*)(bp + (size_t)j * 16 * DIM_ + k0 + 96);
#pragma unroll
    for (int j = 0; j < 6; ++j) {
      acc[0][j] = __builtin_amdgcn_mfma_f32_16x16x32_bf16(A0b, Bb[j], acc[0][j], 0, 0, 0);
      acc[1][j] = __builtin_amdgcn_mfma_f32_16x16x32_bf16(A1b, Bb[j], acc[1][j], 0, 0, 0);
    }
    A0a = nA0a; A1a = nA1a; A0b = nA0b; A1b = nA1b;
#pragma unroll
    for (int j = 0; j < 6; ++j) { Ba[j] = nBa[j]; Bb[j] = nBb[j]; }
  }
  // tail: steps 448 and 480
#pragma unroll
  for (int j = 0; j < 6; ++j) {
    acc[0][j] = __builtin_amdgcn_mfma_f32_16x16x32_bf16(A0a, Ba[j], acc[0][j], 0, 0, 0);
    acc[1][j] = __builtin_amdgcn_mfma_f32_16x16x32_bf16(A1a, Ba[j], acc[1][j], 0, 0, 0);
  }
#pragma unroll
  for (int j = 0; j < 6; ++j) {
    acc[0][j] = __builtin_amdgcn_mfma_f32_16x16x32_bf16(A0b, Bb[j], acc[0][j], 0, 0, 0);
    acc[1][j] = __builtin_amdgcn_mfma_f32_16x16x32_bf16(A1b, Bb[j], acc[1][j], 0, 0, 0);
  }

  // cross-K reduction: wk=1 dumps, wk=0 accumulates
  if (wk) {
#pragma unroll
    for (int i = 0; i < 2; ++i)
#pragma unroll
      for (int j = 0; j < 6; ++j)
#pragma unroll
        for (int r = 0; r < 4; ++r)
          red[(rowbase + i * 16 + lk * 4 + r) * 97 + j * 16 + lr] = acc[i][j][r];
  }
  __syncthreads();
  if (wk == 0) {
#pragma unroll
    for (int i = 0; i < 2; ++i)
#pragma unroll
      for (int j = 0; j < 6; ++j)
#pragma unroll
        for (int r = 0; r < 4; ++r)
          acc[i][j][r] += red[(rowbase + i * 16 + lk * 4 + r) * 97 + j * 16 + lr];

    // epilogue: cols j0,j1=q j2,j3=k j4,j5=v ; row = rowbase + i*16 + lk*4 + r
#pragma unroll
    for (int i = 0; i < 2; ++i) {
#pragma unroll
      for (int r = 0; r < 4; ++r) {
        const int row = rowbase + i * 16 + lk * 4 + r;
        const int p = prs[row];
        float q0v = silu_f(acc[i][0][r]), q1v = silu_f(acc[i][1][r]);
        float k0v = silu_f(acc[i][2][r]), k1v = silu_f(acc[i][3][r]);
        float v0 = silu_f(acc[i][4][r]), v1 = silu_f(acc[i][5][r]);
        float ssq = q0v * q0v + q1v * q1v;
        float ssk = k0v * k0v + k1v * k1v;
        ssq += __shfl_xor(ssq, 1); ssq += __shfl_xor(ssq, 2);
        ssq += __shfl_xor(ssq, 4); ssq += __shfl_xor(ssq, 8);
        ssk += __shfl_xor(ssk, 1); ssk += __shfl_xor(ssk, 2);
        ssk += __shfl_xor(ssk, 4); ssk += __shfl_xor(ssk, 8);
        const float rq = rsqrtf(ssq + 1e-6f), rk = rsqrtf(ssk + 1e-6f);
        if (p >= 0) {
          const int m = p >> 3, s = p & 7;
          const int b = m >> 11, t = m & (T_ - 1);
          float* rb = rec + (((size_t)(b * 8 + s)) * T_ + t) * 128;
          rb[lr]      = k0v * rk;
          rb[16 + lr] = k1v * rk;
          rb[32 + lr] = q0v * rq;
          rb[48 + lr] = q1v * rq;
          rb[64 + lr] = v0;
          rb[80 + lr] = v1;
          if (lr == 0) { rb[96] = decb[p]; rb[97] = rwb[p]; }
        }
      }
    }
  }
}

// ---------------------------------------------------------------- bf16 MFMA GEMM, C = A * B^T (final proj)
template <bool OUT_BF16>
__global__ __launch_bounds__(256) void gemm_bt(const short* __restrict__ A,
                                               const short* __restrict__ Bm,
                                               void* __restrict__ Cout,
                                               int M, int N, int K) {
  __shared__ __align__(16) short As[2][128 * 32];
  __shared__ __align__(16) short Bs[2][128 * 32];
  const int tid = threadIdx.x;
  const int w = tid >> 6, l = tid & 63;
  const int m0 = blockIdx.y * 128, n0 = blockIdx.x * 128;
  const int wr = (w >> 1) * 64, wc = (w & 1) * 64;
  const int rsub = l >> 2, csub = (l & 3) * 8;
  const int lr = l & 15, lk = l >> 4;
  f32x4 acc[4][4] = {};

  auto STAGE = [&](int buf, int k0) {
#pragma unroll
    for (int j = 0; j < 2; ++j) {
      const int ra = w * 32 + j * 16;
      gld_lds16(A  + (size_t)(m0 + ra + rsub) * K + k0 + csub, As[buf] + ra * 32);
      gld_lds16(Bm + (size_t)(n0 + ra + rsub) * K + k0 + csub, Bs[buf] + ra * 32);
    }
  };

  STAGE(0, 0);
  __syncthreads();
  int cur = 0;
  for (int k0 = 0; k0 < K; k0 += 32) {
    if (k0 + 32 < K) STAGE(cur ^ 1, k0 + 32);
    bf16x8 af[4], bfr[4];
#pragma unroll
    for (int i = 0; i < 4; ++i) af[i]  = *(const bf16x8*)(As[cur] + (wr + i * 16 + lr) * 32 + lk * 8);
#pragma unroll
    for (int j = 0; j < 4; ++j) bfr[j] = *(const bf16x8*)(Bs[cur] + (wc + j * 16 + lr) * 32 + lk * 8);
#pragma unroll
    for (int i = 0; i < 4; ++i)
#pragma unroll
      for (int j = 0; j < 4; ++j)
        acc[i][j] = __builtin_amdgcn_mfma_f32_16x16x32_bf16(af[i], bfr[j], acc[i][j], 0, 0, 0);
    __syncthreads();
    cur ^= 1;
  }
#pragma unroll
  for (int i = 0; i < 4; ++i)
#pragma unroll
    for (int j = 0; j < 4; ++j) {
      const size_t row0 = (size_t)m0 + wr + i * 16 + lk * 4;
      const size_t col  = (size_t)n0 + wc + j * 16 + lr;
#pragma unroll
      for (int r = 0; r < 4; ++r) {
        if constexpr (OUT_BF16)
          ((__hip_bfloat16*)Cout)[(row0 + r) * N + col] = __float2bfloat16(acc[i][j][r]);
        else
          ((float*)Cout)[(row0 + r) * N + col] = acc[i][j][r];
      }
    }
}

// ---------------------------------------------------------------- chunked scan: pass 1
__global__ __launch_bounds__(256) void scan_pass1(const float* __restrict__ rec,
                                                  float* __restrict__ ylocal,
                                                  float* __restrict__ Sloc,
                                                  float* __restrict__ Pc,
                                                  float* __restrict__ cumd) {
  __shared__ __align__(16) float R[CL_ * 128];   // 32 KB
  const int blk = blockIdx.x;
  const int bs = blk >> 5, c = blk & (NC_ - 1);
  const int t0 = c * CL_;
  const float* g = rec + ((size_t)bs * T_ + t0) * 128;
  for (int i = threadIdx.x; i < CL_ * 32; i += 256)
    *(float4*)(R + (size_t)i * 4) = *(const float4*)(g + (size_t)i * 4);
  __syncthreads();

  const int w = threadIdx.x >> 6, l = threadIdx.x & 63;
  const int v = w * 8 + (l & 7);
  const int n0 = (l >> 3) * 4;
  float s0 = 0.f, s1 = 0.f, s2 = 0.f, s3 = 0.f;
  float cum = 1.f;
  float* yl = ylocal + ((size_t)bs * T_ + t0) * 32 + v;
  float* cd = cumd + (size_t)bs * T_ + t0;

#pragma unroll 4
  for (int t = 0; t < CL_; ++t) {
    const float* r = R + t * 128;
    const float4 k4 = *(const float4*)(r + n0);
    const float4 q4 = *(const float4*)(r + 32 + n0);
    const float vv = r[64 + v];
    const float d  = r[96];
    cum *= d;
    s0 = fmaf(d, s0, k4.x * vv);
    s1 = fmaf(d, s1, k4.y * vv);
    s2 = fmaf(d, s2, k4.z * vv);
    s3 = fmaf(d, s3, k4.w * vv);
    float p = fmaf(q4.x, s0, fmaf(q4.y, s1, fmaf(q4.z, s2, q4.w * s3)));
    p += __shfl_xor(p, 8); p += __shfl_xor(p, 16); p += __shfl_xor(p, 32);
    if (l < 8) yl[(size_t)t * 32] = p;
    if (threadIdx.x == 0) cd[t] = cum;
  }
  float* sl = Sloc + (((size_t)bs * NC_ + c) * 32 + n0) * 32 + v;
  sl[0] = s0; sl[32] = s1; sl[64] = s2; sl[96] = s3;
  if (threadIdx.x == 0) Pc[bs * NC_ + c] = cum;
}

// ---------------------------------------------------------------- chunked scan: pass 2
__global__ __launch_bounds__(256) void scan_pass2(const float* __restrict__ Sloc,
                                                  const float* __restrict__ Pc,
                                                  const float* __restrict__ S0,
                                                  float* __restrict__ Sin,
                                                  float* __restrict__ Sfin) {
  __shared__ float Ps[NC_];
  const int bs = blockIdx.x;
  if (threadIdx.x < NC_) Ps[threadIdx.x] = Pc[bs * NC_ + threadIdx.x];
  __syncthreads();

  const int e0 = threadIdx.x * 4;
  const float* gl = Sloc + (size_t)bs * NC_ * 1024 + e0;
  float4 S = *(const float4*)(S0 + (size_t)bs * 1024 + e0);
  float* sin_b = Sin + (size_t)bs * NC_ * 1024 + e0;
#pragma unroll 8
  for (int c = 0; c < NC_; ++c) {
    const float4 sl = *(const float4*)(gl + (size_t)c * 1024);
    *(float4*)(sin_b + (size_t)c * 1024) = S;
    const float pc = Ps[c];
    S.x = fmaf(pc, S.x, sl.x);
    S.y = fmaf(pc, S.y, sl.y);
    S.z = fmaf(pc, S.z, sl.z);
    S.w = fmaf(pc, S.w, sl.w);
  }
  *(float4*)(Sfin + (size_t)bs * 1024 + e0) = S;
}

// ---------------------------------------------------------------- chunked scan: pass 3
__global__ __launch_bounds__(256) void scan_pass3(const float* __restrict__ rec,
                                                  const float* __restrict__ ylocal,
                                                  const float* __restrict__ Sin,
                                                  const float* __restrict__ cumd,
                                                  __hip_bfloat16* __restrict__ Y) {
  __shared__ __align__(16) float Ss[1024];
  const int blk = blockIdx.x;
  const int bs = blk >> 5, c = blk & (NC_ - 1);
  const int b = bs >> 3, s = bs & 7;
  const int t0 = c * CL_;
  {
    const float* gs = Sin + ((size_t)bs * NC_ + c) * 1024;
    const int i = threadIdx.x;
    *(float4*)(Ss + (size_t)i * 4) = *(const float4*)(gs + (size_t)i * 4);
  }
  __syncthreads();

  const int w = threadIdx.x >> 6, l = threadIdx.x & 63;
  const int v = l & 31;
#pragma unroll
  for (int i = 0; i < 16; i += 2) {
    const int t = t0 + w * 16 + i + (l >> 5);
    const float* r = rec + ((size_t)bs * T_ + t) * 128;
    float p = 0.f;
#pragma unroll
    for (int nq = 0; nq < 8; ++nq) {
      const float4 q4 = *(const float4*)(r + 32 + nq * 4);
      p = fmaf(q4.x, Ss[(nq * 4 + 0) * 32 + v], p);
      p = fmaf(q4.y, Ss[(nq * 4 + 1) * 32 + v], p);
      p = fmaf(q4.z, Ss[(nq * 4 + 2) * 32 + v], p);
      p = fmaf(q4.w, Ss[(nq * 4 + 3) * 32 + v], p);
    }
    const float wt   = r[97];
    const float cdv  = cumd[(size_t)bs * T_ + t];
    const float yloc = ylocal[((size_t)bs * T_ + t) * 32 + v];
    const long m = (long)b * T_ + t;
    Y[(size_t)m * 256 + s * 32 + v] = __float2bfloat16(wt * (yloc + cdv * p));
  }
}

// ---------------------------------------------------------------- launch
extern "C" void kernel_launch(void* const* d_in, const int* in_sizes, int n_in,
                              void* d_out, int out_size, void* d_ws, size_t ws_size,
                              hipStream_t stream) {
  const float* x       = (const float*)d_in[0];
  const float* Wr      = (const float*)d_in[1];
  const float* Wq      = (const float*)d_in[2];
  const float* Wk      = (const float*)d_in[3];
  const float* Wv      = (const float*)d_in[4];
  const float* Wa      = (const float*)d_in[5];
  const float* A_log   = (const float*)d_in[6];
  const float* dt_bias = (const float*)d_in[7];
  const float* Wo      = (const float*)d_in[8];
  const float* S0      = (const float*)d_in[9];
  float* out = (float*)d_out;

  char* p = (char*)d_ws;
  auto alloc = [&](size_t bytes) -> void* {
    void* r = (void*)p; p += (bytes + 255) & ~(size_t)255; return r;
  };
  __hip_bfloat16* x_bf = (__hip_bfloat16*)alloc((size_t)NTOK * DIM_ * 2);
  __hip_bfloat16* Wg   = (__hip_bfloat16*)alloc((size_t)H_ * 96 * DIM_ * 2);
  float* WT   = (float*)alloc((size_t)DIM_ * RA_N * 4);
  float* RA   = (float*)alloc((size_t)NTOK * RA_N * 4);
  int*   idxb = (int*)  alloc((size_t)NPAIR * 4);
  float* rwb  = (float*)alloc((size_t)NPAIR * 4);
  float* decb = (float*)alloc((size_t)NPAIR * 4);
  int*   cnt  = (int*)  alloc(256);
  int*   pairtok = (int*)alloc((size_t)H_ * NTOK * 4);
  float* recb = (float*)alloc((size_t)NSLOT * T_ * 128 * 4);
  __hip_bfloat16* Yb = (__hip_bfloat16*)alloc((size_t)NTOK * 256 * 2);
  __hip_bfloat16* B2 = (__hip_bfloat16*)alloc((size_t)DIM_ * 256 * 2);
  float* ylocal = (float*)alloc((size_t)NSLOT * T_ * 32 * 4);
  float* Slocb  = (float*)alloc((size_t)NSLOT * NC_ * 1024 * 4);
  float* Pcb    = (float*)alloc((size_t)NSLOT * NC_ * 4);
  float* Sinb   = (float*)alloc((size_t)NSLOT * NC_ * 1024 * 4);
  float* cumdb  = (float*)alloc((size_t)NSLOT * T_ * 4);

  cast_bf16<<<NTOK * DIM_ / 4 / 256, 256, 0, stream>>>(x, x_bf, NTOK * DIM_ / 4);
  build_wg<<<H_ * 96 * DIM_ / 4 / 256, 256, 0, stream>>>(Wq, Wk, Wv, Wg);
  build_b2<<<DIM_ * 256 / 256, 256, 0, stream>>>(Wo, B2);
  build_wt<<<DIM_ * RA_N / 256, 256, 0, stream>>>(Wr, Wa, WT);

  router_gemm<<<NTOK / 16, 256, 0, stream>>>(x, WT, RA);
  router_topk<<<NTOK / 4, 256, 0, stream>>>(RA, A_log, dt_bias, idxb, rwb, decb);

  zero_cnt<<<1, 64, 0, stream>>>(cnt);
  hist_bucket<<<32, 256, 0, stream>>>(idxb, cnt, pairtok);

  grouped_qkv<<<8192, 256, 0, stream>>>(
      (const short*)x_bf, (const short*)Wg, pairtok, cnt, rwb, decb, recb);

  scan_pass1<<<NSLOT * NC_, 256, 0, stream>>>(recb, ylocal, Slocb, Pcb, cumdb);
  scan_pass2<<<NSLOT, 256, 0, stream>>>(Slocb, Pcb, S0, Sinb, out + (size_t)NTOK * DIM_);
  scan_pass3<<<NSLOT * NC_, 256, 0, stream>>>(recb, ylocal, Sinb, cumdb, Yb);

  gemm_bt<false><<<dim3(DIM_ / 128, NTOK / 128), 256, 0, stream>>>(
      (const short*)Yb, (const short*)B2, out, NTOK, DIM_, 256);
}

// Round 11
// 232.945 us; speedup vs baseline: 1.3178x; 1.1045x over previous
//
#include <hip/hip_runtime.h>
#include <hip/hip_bf16.h>

typedef __attribute__((ext_vector_type(8))) short bf16x8;
typedef __attribute__((ext_vector_type(4))) float f32x4;

#define B_   4
#define T_   2048
#define DIM_ 1024
#define H_   64
#define NS_  32
#define K_   8
#define HV_  32
#define NTOK  (B_ * T_)   /* 8192 */
#define RA_N  128         /* router logits(64) | a(64) */
#define CL_   64          /* scan chunk length */
#define NC_   (T_ / CL_)  /* 32 chunks per slot */
#define NSLOT (B_ * K_)   /* 32 */
#define NPAIR (NTOK * K_) /* 65536 */

// ---------------------------------------------------------------- helpers
__device__ __forceinline__ void gld_lds16(const void* g, void* s) {
  __builtin_amdgcn_global_load_lds(
      (const __attribute__((address_space(1))) void*)g,
      (__attribute__((address_space(3))) void*)s, 16, 0, 0);
}
__device__ __forceinline__ float silu_f(float x) { return x / (1.f + expf(-x)); }

// ---------------------------------------------------------------- prep
__global__ __launch_bounds__(256) void cast_bf16(const float* __restrict__ in,
                                                 __hip_bfloat16* __restrict__ out, int n4) {
  int i = blockIdx.x * 256 + threadIdx.x;
  if (i >= n4) return;
  const float4 v = *(const float4*)(in + (size_t)i * 4);
  union { short4 s4; __hip_bfloat16 h[4]; } u;
  u.h[0] = __float2bfloat16(v.x); u.h[1] = __float2bfloat16(v.y);
  u.h[2] = __float2bfloat16(v.z); u.h[3] = __float2bfloat16(v.w);
  *(short4*)(out + (size_t)i * 4) = u.s4;
}

// Wg[h][r][d], r<32: Wq[h*32+r], r<64: Wk[h*32+r-32], else Wv[h*32+r-64]  (bf16)
__global__ __launch_bounds__(256) void build_wg(const float* __restrict__ Wq,
                                                const float* __restrict__ Wk,
                                                const float* __restrict__ Wv,
                                                __hip_bfloat16* __restrict__ Wg) {
  int i = blockIdx.x * 256 + threadIdx.x;           // 6144*1024/4
  int row = i >> 8, c4 = (i & 255) * 4;
  int h = row / 96, r = row - h * 96;
  const float* src = (r < 32) ? (Wq + ((size_t)h * 32 + r) * 1024)
                   : (r < 64) ? (Wk + ((size_t)h * 32 + r - 32) * 1024)
                              : (Wv + ((size_t)h * 32 + r - 64) * 1024);
  const float4 v = *(const float4*)(src + c4);
  union { short4 s4; __hip_bfloat16 hh[4]; } u;
  u.hh[0] = __float2bfloat16(v.x); u.hh[1] = __float2bfloat16(v.y);
  u.hh[2] = __float2bfloat16(v.z); u.hh[3] = __float2bfloat16(v.w);
  *(short4*)(Wg + (size_t)row * 1024 + c4) = u.s4;
}

// B2[d][s*32+v] = Wo[d][v]  (slot-replicated Wo, bf16), 1024x256
__global__ __launch_bounds__(256) void build_b2(const float* __restrict__ Wo,
                                                __hip_bfloat16* __restrict__ B2) {
  int i = blockIdx.x * 256 + threadIdx.x;
  int d = i >> 8, c = i & 255;
  B2[i] = __float2bfloat16(Wo[d * 32 + (c & 31)]);
}

// WT[d][h] = (h<64 ? Wr : Wa)[h][d]   fp32, 1024x128
__global__ __launch_bounds__(256) void build_wt(const float* __restrict__ Wr,
                                                const float* __restrict__ Wa,
                                                float* __restrict__ WT) {
  int i = blockIdx.x * 256 + threadIdx.x;
  int d = i >> 7, h = i & 127;
  WT[i] = (h < 64) ? Wr[h * 1024 + d] : Wa[(h - 64) * 1024 + d];
}

// ---------------------------------------------------------------- router GEMM (fp32 exact, split-K x2)
__global__ __launch_bounds__(256) void router_gemm(const float* __restrict__ x,
                                                   const float* __restrict__ WT,
                                                   float* __restrict__ RA) {
  __shared__ float Lp[4][8][128];
  const int w = threadIdx.x >> 6, l = threadIdx.x & 63;
  const int t0 = blockIdx.x * 16 + (w >> 1) * 8;
  const int d0 = (w & 1) * 512;
  float a0[8] = {}, a1[8] = {};
  for (int d = d0; d < d0 + 512; d += 4) {
    float4 xv[8];
#pragma unroll
    for (int i = 0; i < 8; ++i) xv[i] = *(const float4*)(x + (size_t)(t0 + i) * DIM_ + d);
#pragma unroll
    for (int j = 0; j < 4; ++j) {
      const float w0 = WT[(d + j) * RA_N + l];
      const float w1 = WT[(d + j) * RA_N + 64 + l];
#pragma unroll
      for (int i = 0; i < 8; ++i) {
        const float xs = ((const float*)&xv[i])[j];
        a0[i] = fmaf(xs, w0, a0[i]);
        a1[i] = fmaf(xs, w1, a1[i]);
      }
    }
  }
#pragma unroll
  for (int i = 0; i < 8; ++i) { Lp[w][i][l] = a0[i]; Lp[w][i][64 + l] = a1[i]; }
  __syncthreads();
  for (int o = threadIdx.x; o < 2048; o += 256) {
    const int ti = o >> 7, cc = o & 127;
    const int wp = (ti >> 3) * 2;
    RA[(size_t)(blockIdx.x * 16 + ti) * RA_N + cc] = Lp[wp][ti & 7][cc] + Lp[wp + 1][ti & 7][cc];
  }
}

// ---------------------------------------------------------------- top-k + decay (1 wave / token)
__global__ __launch_bounds__(256) void router_topk(const float* __restrict__ RA,
                                                   const float* __restrict__ A_log,
                                                   const float* __restrict__ dt_bias,
                                                   int* __restrict__ idxb,
                                                   float* __restrict__ rwb,
                                                   float* __restrict__ decb) {
  const int w = threadIdx.x >> 6, l = threadIdx.x & 63;
  const int m = blockIdx.x * 4 + w;
  float zcur = RA[(size_t)m * RA_N + l];
  const int idx = l;
  float z0 = 0.f, myz = 0.f;
  int myh = 0;
#pragma unroll
  for (int i = 0; i < 8; ++i) {
    float v = zcur; int vi = idx;
#pragma unroll
    for (int off = 1; off < 64; off <<= 1) {
      float ov = __shfl_xor(v, off);
      int   oi = __shfl_xor(vi, off);
      if (ov > v || (ov == v && oi < vi)) { v = ov; vi = oi; }
    }
    if (i == 0) z0 = v;
    if (l == i) { myz = v; myh = vi; }
    if (idx == vi) zcur = -__builtin_inff();
  }
  float e = (l < 8) ? expf(myz - z0) : 0.f;
  float es = e;
  es += __shfl_xor(es, 1); es += __shfl_xor(es, 2); es += __shfl_xor(es, 4);
  if (l < 8) {
    const float a  = RA[(size_t)m * RA_N + 64 + myh];
    const float xb = a + dt_bias[myh];
    const float dt = (xb > 20.f) ? xb : log1pf(expf(xb));
    idxb[m * 8 + l] = myh;
    rwb [m * 8 + l] = e / es;
    decb[m * 8 + l] = expf(-expf(A_log[myh]) * dt);
  }
}

// ---------------------------------------------------------------- head bucketing
__global__ void zero_cnt(int* __restrict__ cnt) {
  if (threadIdx.x < H_) cnt[threadIdx.x] = 0;
}

// LDS-aggregated bucketing (R7): 32 blocks x 2048 pairs, per-block LDS
// histogram, one global atomicAdd per (head, block). Bucket-internal order
// nondeterministic; rec rows keyed by pair id -> d_out deterministic.
__global__ __launch_bounds__(256) void hist_bucket(const int* __restrict__ idxb,
                                                   int* __restrict__ cnt,
                                                   int* __restrict__ pairtok) {
  __shared__ int lh[H_];
  __shared__ int lcur[H_];
  const int tid = threadIdx.x;
  if (tid < H_) lh[tid] = 0;
  __syncthreads();
  const int base = blockIdx.x * (NPAIR / 32);   // 2048 pairs/block
  int hs[8];
#pragma unroll
  for (int j = 0; j < 8; ++j) {
    hs[j] = idxb[base + j * 256 + tid];
    atomicAdd(&lh[hs[j]], 1);
  }
  __syncthreads();
  if (tid < H_) lcur[tid] = atomicAdd(&cnt[tid], lh[tid]);
  __syncthreads();
#pragma unroll
  for (int j = 0; j < 8; ++j) {
    const int pos = atomicAdd(&lcur[hs[j]], 1);
    pairtok[hs[j] * NTOK + pos] = base + j * 256 + tid;
  }
}

// ---------------------------------------------------------------- grouped QKV projection
// T4 pipeline: global_load_lds (zero-VGPR in-flight loads) + counted vmcnt +
// raw s_barrier. 3-buffer LDS rotation, 2 stages (10 loads/wave) always in
// flight. Each wave issues exactly 5 glds/stage: 2 A chunks (its 32 gathered
// rows, its K-half) + 3 B chunks (half of its K-half's 96 weight rows; B
// shared between the two row-group waves of the same K-half). XOR slot
// swizzle (source-side + ds_read-side, rule #21) cuts 8-way->4-way bank
// conflicts. Reduction buffer aliases staging LDS (dead after K-loop).
__global__ __launch_bounds__(256, 2) void grouped_qkv(const short* __restrict__ x_bf,
                                                      const short* __restrict__ Wg,
                                                      const int* __restrict__ pairtok,
                                                      const int* __restrict__ cnt,
                                                      const float* __restrict__ rwb,
                                                      const float* __restrict__ decb,
                                                      float* __restrict__ rec) {
  const int bid = blockIdx.x;
  const int h = (bid & 7) | (((bid >> 3) & 7) << 3);  // bid%8 == h%8 (XCD affinity)
  const int c = bid >> 6;                             // 0..127 chunk of 64 rows
  const int n = cnt[h];
  if (c * 64 >= n) return;
  // stage layout (shorts): A(wr,wk) at (wr*2+wk)*1024 (2 chunks x 512);
  // B(wk) at 4096 + wk*3072 (6 chunks x 512). 10240 shorts = 20 KB/stage.
  __shared__ __align__(16) short stg[3][10240];       // 60 KB
  __shared__ int prs[64];
  float* red = (float*)&stg[0][0];                    // aliases staging after K-loop

  if (threadIdx.x < 64) {
    const int ri = c * 64 + threadIdx.x;
    prs[threadIdx.x] = (ri < n) ? pairtok[h * NTOK + ri] : -1;
  }
  __syncthreads();

  const int w = threadIdx.x >> 6, l = threadIdx.x & 63;
  const int wr = w >> 1, wk = w & 1;                  // row-group, K-half
  const int lr = l & 15, lk = l >> 4;
  const int rowbase = wr * 32;
  const int fallback = prs[0] >> 3;

  // staging lane decode: row rsub within 16-row chunk, swizzled source slot
  const int rsub = l >> 2;
  const int csl = (((l & 3) ^ (rsub & 3)) << 3);      // swizzled col (shorts)
  const int pa0 = prs[rowbase + rsub], pa1 = prs[rowbase + 16 + rsub];
  const long ta0 = (pa0 >= 0) ? (long)(pa0 >> 3) : fallback;
  const long ta1 = (pa1 >= 0) ? (long)(pa1 >> 3) : fallback;
  const short* sa0 = x_bf + ta0 * DIM_ + wk * 512 + csl;
  const short* sa1 = x_bf + ta1 * DIM_ + wk * 512 + csl;
  // B: wave (wr,wk) stages chunks wr*3..wr*3+2 of its K-half
  const short* sb = Wg + ((size_t)h * 96 + wr * 48 + rsub) * DIM_ + wk * 512 + csl;
  const int aoff = (wr * 2 + wk) * 1024;              // my A area (shorts)
  const int boff = 4096 + wk * 3072;                  // my B area (shorts)

  auto STAGE = [&](int s, int t) {
    const int k0 = t * 32;
    short* bb = stg[s];
    gld_lds16(sa0 + k0, bb + aoff);
    gld_lds16(sa1 + k0, bb + aoff + 512);
#pragma unroll
    for (int j = 0; j < 3; ++j)
      gld_lds16(sb + (size_t)(j * 16) * DIM_ + k0, bb + boff + (wr * 3 + j) * 512);
  };

  f32x4 acc[2][6] = {};
  STAGE(0, 0);
  STAGE(1, 1);

  const int sl8 = ((lk ^ (lr & 3)) << 3);             // ds_read swizzled slot (shorts)
  int sC = 0, sN = 1, sNN = 2;
  for (int t = 0; t < 16; ++t) {
    if (t < 15) asm volatile("s_waitcnt vmcnt(5) lgkmcnt(0)" ::: "memory");
    else        asm volatile("s_waitcnt vmcnt(0) lgkmcnt(0)" ::: "memory");
    __builtin_amdgcn_s_barrier();
    __builtin_amdgcn_sched_barrier(0);
    if (t + 2 < 16) STAGE(sNN, t + 2);
    const short* bb = stg[sC];
    const bf16x8 a0 = *(const bf16x8*)(bb + aoff + lr * 32 + sl8);
    const bf16x8 a1 = *(const bf16x8*)(bb + aoff + 512 + lr * 32 + sl8);
#pragma unroll
    for (int j = 0; j < 6; ++j) {
      const bf16x8 bj = *(const bf16x8*)(bb + boff + j * 512 + lr * 32 + sl8);
      acc[0][j] = __builtin_amdgcn_mfma_f32_16x16x32_bf16(a0, bj, acc[0][j], 0, 0, 0);
      acc[1][j] = __builtin_amdgcn_mfma_f32_16x16x32_bf16(a1, bj, acc[1][j], 0, 0, 0);
    }
    const int tmp = sC; sC = sN; sN = sNN; sNN = tmp;
  }
  __syncthreads();                                    // staging dead; red may alias

  // cross-K reduction: wk=1 dumps, wk=0 accumulates
  if (wk) {
#pragma unroll
    for (int i = 0; i < 2; ++i)
#pragma unroll
      for (int j = 0; j < 6; ++j)
#pragma unroll
        for (int r = 0; r < 4; ++r)
          red[(rowbase + i * 16 + lk * 4 + r) * 97 + j * 16 + lr] = acc[i][j][r];
  }
  __syncthreads();
  if (wk == 0) {
#pragma unroll
    for (int i = 0; i < 2; ++i)
#pragma unroll
      for (int j = 0; j < 6; ++j)
#pragma unroll
        for (int r = 0; r < 4; ++r)
          acc[i][j][r] += red[(rowbase + i * 16 + lk * 4 + r) * 97 + j * 16 + lr];

    // epilogue: cols j0,j1=q j2,j3=k j4,j5=v ; row = rowbase + i*16 + lk*4 + r
#pragma unroll
    for (int i = 0; i < 2; ++i) {
#pragma unroll
      for (int r = 0; r < 4; ++r) {
        const int row = rowbase + i * 16 + lk * 4 + r;
        const int p = prs[row];
        float q0v = silu_f(acc[i][0][r]), q1v = silu_f(acc[i][1][r]);
        float k0v = silu_f(acc[i][2][r]), k1v = silu_f(acc[i][3][r]);
        float v0 = silu_f(acc[i][4][r]), v1 = silu_f(acc[i][5][r]);
        float ssq = q0v * q0v + q1v * q1v;
        float ssk = k0v * k0v + k1v * k1v;
        ssq += __shfl_xor(ssq, 1); ssq += __shfl_xor(ssq, 2);
        ssq += __shfl_xor(ssq, 4); ssq += __shfl_xor(ssq, 8);
        ssk += __shfl_xor(ssk, 1); ssk += __shfl_xor(ssk, 2);
        ssk += __shfl_xor(ssk, 4); ssk += __shfl_xor(ssk, 8);
        const float rq = rsqrtf(ssq + 1e-6f), rk = rsqrtf(ssk + 1e-6f);
        if (p >= 0) {
          const int m = p >> 3, s = p & 7;
          const int b = m >> 11, t = m & (T_ - 1);
          float* rb = rec + (((size_t)(b * 8 + s)) * T_ + t) * 128;
          rb[lr]      = k0v * rk;
          rb[16 + lr] = k1v * rk;
          rb[32 + lr] = q0v * rq;
          rb[48 + lr] = q1v * rq;
          rb[64 + lr] = v0;
          rb[80 + lr] = v1;
          if (lr == 0) { rb[96] = decb[p]; rb[97] = rwb[p]; }
        }
      }
    }
  }
}

// ---------------------------------------------------------------- bf16 MFMA GEMM, C = A * B^T (final proj)
template <bool OUT_BF16>
__global__ __launch_bounds__(256) void gemm_bt(const short* __restrict__ A,
                                               const short* __restrict__ Bm,
                                               void* __restrict__ Cout,
                                               int M, int N, int K) {
  __shared__ __align__(16) short As[2][128 * 32];
  __shared__ __align__(16) short Bs[2][128 * 32];
  const int tid = threadIdx.x;
  const int w = tid >> 6, l = tid & 63;
  const int m0 = blockIdx.y * 128, n0 = blockIdx.x * 128;
  const int wr = (w >> 1) * 64, wc = (w & 1) * 64;
  const int rsub = l >> 2, csub = (l & 3) * 8;
  const int lr = l & 15, lk = l >> 4;
  f32x4 acc[4][4] = {};

  auto STAGE = [&](int buf, int k0) {
#pragma unroll
    for (int j = 0; j < 2; ++j) {
      const int ra = w * 32 + j * 16;
      gld_lds16(A  + (size_t)(m0 + ra + rsub) * K + k0 + csub, As[buf] + ra * 32);
      gld_lds16(Bm + (size_t)(n0 + ra + rsub) * K + k0 + csub, Bs[buf] + ra * 32);
    }
  };

  STAGE(0, 0);
  __syncthreads();
  int cur = 0;
  for (int k0 = 0; k0 < K; k0 += 32) {
    if (k0 + 32 < K) STAGE(cur ^ 1, k0 + 32);
    bf16x8 af[4], bfr[4];
#pragma unroll
    for (int i = 0; i < 4; ++i) af[i]  = *(const bf16x8*)(As[cur] + (wr + i * 16 + lr) * 32 + lk * 8);
#pragma unroll
    for (int j = 0; j < 4; ++j) bfr[j] = *(const bf16x8*)(Bs[cur] + (wc + j * 16 + lr) * 32 + lk * 8);
#pragma unroll
    for (int i = 0; i < 4; ++i)
#pragma unroll
      for (int j = 0; j < 4; ++j)
        acc[i][j] = __builtin_amdgcn_mfma_f32_16x16x32_bf16(af[i], bfr[j], acc[i][j], 0, 0, 0);
    __syncthreads();
    cur ^= 1;
  }
#pragma unroll
  for (int i = 0; i < 4; ++i)
#pragma unroll
    for (int j = 0; j < 4; ++j) {
      const size_t row0 = (size_t)m0 + wr + i * 16 + lk * 4;
      const size_t col  = (size_t)n0 + wc + j * 16 + lr;
#pragma unroll
      for (int r = 0; r < 4; ++r) {
        if constexpr (OUT_BF16)
          ((__hip_bfloat16*)Cout)[(row0 + r) * N + col] = __float2bfloat16(acc[i][j][r]);
        else
          ((float*)Cout)[(row0 + r) * N + col] = acc[i][j][r];
      }
    }
}

// ---------------------------------------------------------------- chunked scan: pass 1
__global__ __launch_bounds__(256) void scan_pass1(const float* __restrict__ rec,
                                                  float* __restrict__ ylocal,
                                                  float* __restrict__ Sloc,
                                                  float* __restrict__ Pc,
                                                  float* __restrict__ cumd) {
  __shared__ __align__(16) float R[CL_ * 128];   // 32 KB
  const int blk = blockIdx.x;
  const int bs = blk >> 5, c = blk & (NC_ - 1);
  const int t0 = c * CL_;
  const float* g = rec + ((size_t)bs * T_ + t0) * 128;
  for (int i = threadIdx.x; i < CL_ * 32; i += 256)
    *(float4*)(R + (size_t)i * 4) = *(const float4*)(g + (size_t)i * 4);
  __syncthreads();

  const int w = threadIdx.x >> 6, l = threadIdx.x & 63;
  const int v = w * 8 + (l & 7);
  const int n0 = (l >> 3) * 4;
  float s0 = 0.f, s1 = 0.f, s2 = 0.f, s3 = 0.f;
  float cum = 1.f;
  float* yl = ylocal + ((size_t)bs * T_ + t0) * 32 + v;
  float* cd = cumd + (size_t)bs * T_ + t0;

#pragma unroll 4
  for (int t = 0; t < CL_; ++t) {
    const float* r = R + t * 128;
    const float4 k4 = *(const float4*)(r + n0);
    const float4 q4 = *(const float4*)(r + 32 + n0);
    const float vv = r[64 + v];
    const float d  = r[96];
    cum *= d;
    s0 = fmaf(d, s0, k4.x * vv);
    s1 = fmaf(d, s1, k4.y * vv);
    s2 = fmaf(d, s2, k4.z * vv);
    s3 = fmaf(d, s3, k4.w * vv);
    float p = fmaf(q4.x, s0, fmaf(q4.y, s1, fmaf(q4.z, s2, q4.w * s3)));
    p += __shfl_xor(p, 8); p += __shfl_xor(p, 16); p += __shfl_xor(p, 32);
    if (l < 8) yl[(size_t)t * 32] = p;
    if (threadIdx.x == 0) cd[t] = cum;
  }
  float* sl = Sloc + (((size_t)bs * NC_ + c) * 32 + n0) * 32 + v;
  sl[0] = s0; sl[32] = s1; sl[64] = s2; sl[96] = s3;
  if (threadIdx.x == 0) Pc[bs * NC_ + c] = cum;
}

// ---------------------------------------------------------------- chunked scan: pass 2
__global__ __launch_bounds__(256) void scan_pass2(const float* __restrict__ Sloc,
                                                  const float* __restrict__ Pc,
                                                  const float* __restrict__ S0,
                                                  float* __restrict__ Sin,
                                                  float* __restrict__ Sfin) {
  __shared__ float Ps[NC_];
  const int bs = blockIdx.x;
  if (threadIdx.x < NC_) Ps[threadIdx.x] = Pc[bs * NC_ + threadIdx.x];
  __syncthreads();

  const int e0 = threadIdx.x * 4;
  const float* gl = Sloc + (size_t)bs * NC_ * 1024 + e0;
  float4 S = *(const float4*)(S0 + (size_t)bs * 1024 + e0);
  float* sin_b = Sin + (size_t)bs * NC_ * 1024 + e0;
#pragma unroll 8
  for (int c = 0; c < NC_; ++c) {
    const float4 sl = *(const float4*)(gl + (size_t)c * 1024);
    *(float4*)(sin_b + (size_t)c * 1024) = S;
    const float pc = Ps[c];
    S.x = fmaf(pc, S.x, sl.x);
    S.y = fmaf(pc, S.y, sl.y);
    S.z = fmaf(pc, S.z, sl.z);
    S.w = fmaf(pc, S.w, sl.w);
  }
  *(float4*)(Sfin + (size_t)bs * 1024 + e0) = S;
}

// ---------------------------------------------------------------- chunked scan: pass 3
__global__ __launch_bounds__(256) void scan_pass3(const float* __restrict__ rec,
                                                  const float* __restrict__ ylocal,
                                                  const float* __restrict__ Sin,
                                                  const float* __restrict__ cumd,
                                                  __hip_bfloat16* __restrict__ Y) {
  __shared__ __align__(16) float Ss[1024];
  const int blk = blockIdx.x;
  const int bs = blk >> 5, c = blk & (NC_ - 1);
  const int b = bs >> 3, s = bs & 7;
  const int t0 = c * CL_;
  {
    const float* gs = Sin + ((size_t)bs * NC_ + c) * 1024;
    const int i = threadIdx.x;
    *(float4*)(Ss + (size_t)i * 4) = *(const float4*)(gs + (size_t)i * 4);
  }
  __syncthreads();

  const int w = threadIdx.x >> 6, l = threadIdx.x & 63;
  const int v = l & 31;
#pragma unroll
  for (int i = 0; i < 16; i += 2) {
    const int t = t0 + w * 16 + i + (l >> 5);
    const float* r = rec + ((size_t)bs * T_ + t) * 128;
    float p = 0.f;
#pragma unroll
    for (int nq = 0; nq < 8; ++nq) {
      const float4 q4 = *(const float4*)(r + 32 + nq * 4);
      p = fmaf(q4.x, Ss[(nq * 4 + 0) * 32 + v], p);
      p = fmaf(q4.y, Ss[(nq * 4 + 1) * 32 + v], p);
      p = fmaf(q4.z, Ss[(nq * 4 + 2) * 32 + v], p);
      p = fmaf(q4.w, Ss[(nq * 4 + 3) * 32 + v], p);
    }
    const float wt   = r[97];
    const float cdv  = cumd[(size_t)bs * T_ + t];
    const float yloc = ylocal[((size_t)bs * T_ + t) * 32 + v];
    const long m = (long)b * T_ + t;
    Y[(size_t)m * 256 + s * 32 + v] = __float2bfloat16(wt * (yloc + cdv * p));
  }
}

// ---------------------------------------------------------------- launch
extern "C" void kernel_launch(void* const* d_in, const int* in_sizes, int n_in,
                              void* d_out, int out_size, void* d_ws, size_t ws_size,
                              hipStream_t stream) {
  const float* x       = (const float*)d_in[0];
  const float* Wr      = (const float*)d_in[1];
  const float* Wq      = (const float*)d_in[2];
  const float* Wk      = (const float*)d_in[3];
  const float* Wv      = (const float*)d_in[4];
  const float* Wa      = (const float*)d_in[5];
  const float* A_log   = (const float*)d_in[6];
  const float* dt_bias = (const float*)d_in[7];
  const float* Wo      = (const float*)d_in[8];
  const float* S0      = (const float*)d_in[9];
  float* out = (float*)d_out;

  char* p = (char*)d_ws;
  auto alloc = [&](size_t bytes) -> void* {
    void* r = (void*)p; p += (bytes + 255) & ~(size_t)255; return r;
  };
  __hip_bfloat16* x_bf = (__hip_bfloat16*)alloc((size_t)NTOK * DIM_ * 2);
  __hip_bfloat16* Wg   = (__hip_bfloat16*)alloc((size_t)H_ * 96 * DIM_ * 2);
  float* WT   = (float*)alloc((size_t)DIM_ * RA_N * 4);
  float* RA   = (float*)alloc((size_t)NTOK * RA_N * 4);
  int*   idxb = (int*)  alloc((size_t)NPAIR * 4);
  float* rwb  = (float*)alloc((size_t)NPAIR * 4);
  float* decb = (float*)alloc((size_t)NPAIR * 4);
  int*   cnt  = (int*)  alloc(256);
  int*   pairtok = (int*)alloc((size_t)H_ * NTOK * 4);
  float* recb = (float*)alloc((size_t)NSLOT * T_ * 128 * 4);
  __hip_bfloat16* Yb = (__hip_bfloat16*)alloc((size_t)NTOK * 256 * 2);
  __hip_bfloat16* B2 = (__hip_bfloat16*)alloc((size_t)DIM_ * 256 * 2);
  float* ylocal = (float*)alloc((size_t)NSLOT * T_ * 32 * 4);
  float* Slocb  = (float*)alloc((size_t)NSLOT * NC_ * 1024 * 4);
  float* Pcb    = (float*)alloc((size_t)NSLOT * NC_ * 4);
  float* Sinb   = (float*)alloc((size_t)NSLOT * NC_ * 1024 * 4);
  float* cumdb  = (float*)alloc((size_t)NSLOT * T_ * 4);

  cast_bf16<<<NTOK * DIM_ / 4 / 256, 256, 0, stream>>>(x, x_bf, NTOK * DIM_ / 4);
  build_wg<<<H_ * 96 * DIM_ / 4 / 256, 256, 0, stream>>>(Wq, Wk, Wv, Wg);
  build_b2<<<DIM_ * 256 / 256, 256, 0, stream>>>(Wo, B2);
  build_wt<<<DIM_ * RA_N / 256, 256, 0, stream>>>(Wr, Wa, WT);

  router_gemm<<<NTOK / 16, 256, 0, stream>>>(x, WT, RA);
  router_topk<<<NTOK / 4, 256, 0, stream>>>(RA, A_log, dt_bias, idxb, rwb, decb);

  zero_cnt<<<1, 64, 0, stream>>>(cnt);
  hist_bucket<<<32, 256, 0, stream>>>(idxb, cnt, pairtok);

  grouped_qkv<<<8192, 256, 0, stream>>>(
      (const short*)x_bf, (const short*)Wg, pairtok, cnt, rwb, decb, recb);

  scan_pass1<<<NSLOT * NC_, 256, 0, stream>>>(recb, ylocal, Slocb, Pcb, cumdb);
  scan_pass2<<<NSLOT, 256, 0, stream>>>(Slocb, Pcb, S0, Sinb, out + (size_t)NTOK * DIM_);
  scan_pass3<<<NSLOT * NC_, 256, 0, stream>>>(recb, ylocal, Sinb, cumdb, Yb);

  gemm_bt<false><<<dim3(DIM_ / 128, NTOK / 128), 256, 0, stream>>>(
      (const short*)Yb, (const short*)B2, out, NTOK, DIM_, 256);
}

// Round 13
// 210.395 us; speedup vs baseline: 1.4590x; 1.1072x over previous
//
#include <hip/hip_runtime.h>
#include <hip/hip_bf16.h>

typedef __attribute__((ext_vector_type(8))) short bf16x8;
typedef __attribute__((ext_vector_type(4))) float f32x4;

#define B_   4
#define T_   2048
#define DIM_ 1024
#define H_   64
#define NS_  32
#define K_   8
#define HV_  32
#define NTOK  (B_ * T_)   /* 8192 */
#define RA_N  128         /* router logits(64) | a(64) */
#define CL_   64          /* scan chunk length */
#define NC_   (T_ / CL_)  /* 32 chunks per slot */
#define NSLOT (B_ * K_)   /* 32 */
#define NPAIR (NTOK * K_) /* 65536 */

// ---------------------------------------------------------------- helpers
__device__ __forceinline__ void gld_lds16(const void* g, void* s) {
  __builtin_amdgcn_global_load_lds(
      (const __attribute__((address_space(1))) void*)g,
      (__attribute__((address_space(3))) void*)s, 16, 0, 0);
}
__device__ __forceinline__ float silu_f(float x) { return x / (1.f + expf(-x)); }

// ---------------------------------------------------------------- prep
__global__ __launch_bounds__(256) void cast_bf16(const float* __restrict__ in,
                                                 __hip_bfloat16* __restrict__ out, int n4) {
  int i = blockIdx.x * 256 + threadIdx.x;
  if (i >= n4) return;
  const float4 v = *(const float4*)(in + (size_t)i * 4);
  union { short4 s4; __hip_bfloat16 h[4]; } u;
  u.h[0] = __float2bfloat16(v.x); u.h[1] = __float2bfloat16(v.y);
  u.h[2] = __float2bfloat16(v.z); u.h[3] = __float2bfloat16(v.w);
  *(short4*)(out + (size_t)i * 4) = u.s4;
}

// Wg[h][r][d], r<32: Wq[h*32+r], r<64: Wk[h*32+r-32], else Wv[h*32+r-64]  (bf16)
__global__ __launch_bounds__(256) void build_wg(const float* __restrict__ Wq,
                                                const float* __restrict__ Wk,
                                                const float* __restrict__ Wv,
                                                __hip_bfloat16* __restrict__ Wg) {
  int i = blockIdx.x * 256 + threadIdx.x;           // 6144*1024/4
  int row = i >> 8, c4 = (i & 255) * 4;
  int h = row / 96, r = row - h * 96;
  const float* src = (r < 32) ? (Wq + ((size_t)h * 32 + r) * 1024)
                   : (r < 64) ? (Wk + ((size_t)h * 32 + r - 32) * 1024)
                              : (Wv + ((size_t)h * 32 + r - 64) * 1024);
  const float4 v = *(const float4*)(src + c4);
  union { short4 s4; __hip_bfloat16 hh[4]; } u;
  u.hh[0] = __float2bfloat16(v.x); u.hh[1] = __float2bfloat16(v.y);
  u.hh[2] = __float2bfloat16(v.z); u.hh[3] = __float2bfloat16(v.w);
  *(short4*)(Wg + (size_t)row * 1024 + c4) = u.s4;
}

// B2[d][s*32+v] = Wo[d][v]  (slot-replicated Wo, bf16), 1024x256
__global__ __launch_bounds__(256) void build_b2(const float* __restrict__ Wo,
                                                __hip_bfloat16* __restrict__ B2) {
  int i = blockIdx.x * 256 + threadIdx.x;
  int d = i >> 8, c = i & 255;
  B2[i] = __float2bfloat16(Wo[d * 32 + (c & 31)]);
}

// WT[d][h] = (h<64 ? Wr : Wa)[h][d]   fp32, 1024x128
__global__ __launch_bounds__(256) void build_wt(const float* __restrict__ Wr,
                                                const float* __restrict__ Wa,
                                                float* __restrict__ WT) {
  int i = blockIdx.x * 256 + threadIdx.x;
  int d = i >> 7, h = i & 127;
  WT[i] = (h < 64) ? Wr[h * 1024 + d] : Wa[(h - 64) * 1024 + d];
}

// ---------------------------------------------------------------- router GEMM (fp32 exact, split-K x2)
__global__ __launch_bounds__(256) void router_gemm(const float* __restrict__ x,
                                                   const float* __restrict__ WT,
                                                   float* __restrict__ RA) {
  __shared__ float Lp[4][8][128];
  const int w = threadIdx.x >> 6, l = threadIdx.x & 63;
  const int t0 = blockIdx.x * 16 + (w >> 1) * 8;
  const int d0 = (w & 1) * 512;
  float a0[8] = {}, a1[8] = {};
  for (int d = d0; d < d0 + 512; d += 4) {
    float4 xv[8];
#pragma unroll
    for (int i = 0; i < 8; ++i) xv[i] = *(const float4*)(x + (size_t)(t0 + i) * DIM_ + d);
#pragma unroll
    for (int j = 0; j < 4; ++j) {
      const float w0 = WT[(d + j) * RA_N + l];
      const float w1 = WT[(d + j) * RA_N + 64 + l];
#pragma unroll
      for (int i = 0; i < 8; ++i) {
        const float xs = ((const float*)&xv[i])[j];
        a0[i] = fmaf(xs, w0, a0[i]);
        a1[i] = fmaf(xs, w1, a1[i]);
      }
    }
  }
#pragma unroll
  for (int i = 0; i < 8; ++i) { Lp[w][i][l] = a0[i]; Lp[w][i][64 + l] = a1[i]; }
  __syncthreads();
  for (int o = threadIdx.x; o < 2048; o += 256) {
    const int ti = o >> 7, cc = o & 127;
    const int wp = (ti >> 3) * 2;
    RA[(size_t)(blockIdx.x * 16 + ti) * RA_N + cc] = Lp[wp][ti & 7][cc] + Lp[wp + 1][ti & 7][cc];
  }
}

// ---------------------------------------------------------------- top-k + decay (1 wave / token)
__global__ __launch_bounds__(256) void router_topk(const float* __restrict__ RA,
                                                   const float* __restrict__ A_log,
                                                   const float* __restrict__ dt_bias,
                                                   int* __restrict__ idxb,
                                                   float* __restrict__ rwb,
                                                   float* __restrict__ decb) {
  const int w = threadIdx.x >> 6, l = threadIdx.x & 63;
  const int m = blockIdx.x * 4 + w;
  float zcur = RA[(size_t)m * RA_N + l];
  const int idx = l;
  float z0 = 0.f, myz = 0.f;
  int myh = 0;
#pragma unroll
  for (int i = 0; i < 8; ++i) {
    float v = zcur; int vi = idx;
#pragma unroll
    for (int off = 1; off < 64; off <<= 1) {
      float ov = __shfl_xor(v, off);
      int   oi = __shfl_xor(vi, off);
      if (ov > v || (ov == v && oi < vi)) { v = ov; vi = oi; }
    }
    if (i == 0) z0 = v;
    if (l == i) { myz = v; myh = vi; }
    if (idx == vi) zcur = -__builtin_inff();
  }
  float e = (l < 8) ? expf(myz - z0) : 0.f;
  float es = e;
  es += __shfl_xor(es, 1); es += __shfl_xor(es, 2); es += __shfl_xor(es, 4);
  if (l < 8) {
    const float a  = RA[(size_t)m * RA_N + 64 + myh];
    const float xb = a + dt_bias[myh];
    const float dt = (xb > 20.f) ? xb : log1pf(expf(xb));
    idxb[m * 8 + l] = myh;
    rwb [m * 8 + l] = e / es;
    decb[m * 8 + l] = expf(-expf(A_log[myh]) * dt);
  }
}

// ---------------------------------------------------------------- head bucketing
__global__ void zero_cnt(int* __restrict__ cnt) {
  if (threadIdx.x < H_) cnt[threadIdx.x] = 0;
}

// LDS-aggregated bucketing (R7).
__global__ __launch_bounds__(256) void hist_bucket(const int* __restrict__ idxb,
                                                   int* __restrict__ cnt,
                                                   int* __restrict__ pairtok) {
  __shared__ int lh[H_];
  __shared__ int lcur[H_];
  const int tid = threadIdx.x;
  if (tid < H_) lh[tid] = 0;
  __syncthreads();
  const int base = blockIdx.x * (NPAIR / 32);   // 2048 pairs/block
  int hs[8];
#pragma unroll
  for (int j = 0; j < 8; ++j) {
    hs[j] = idxb[base + j * 256 + tid];
    atomicAdd(&lh[hs[j]], 1);
  }
  __syncthreads();
  if (tid < H_) lcur[tid] = atomicAdd(&cnt[tid], lh[tid]);
  __syncthreads();
#pragma unroll
  for (int j = 0; j < 8; ++j) {
    const int pos = atomicAdd(&lcur[hs[j]], 1);
    pairtok[hs[j] * NTOK + pos] = base + j * 256 + tid;
  }
}

// ---------------------------------------------------------------- grouped QKV projection
// No split-K (R12's A-region collision is structurally impossible): 4 waves =
// 4 private row-groups of 16, all 96 cols, full K. 128B-segment staging
// (8 rows per gld_lds16) -> half the memory transactions of R11's 64B layout.
// Stage = A[64][64] + B[96][64] shorts = 20KB; 2 buffers = 40KB -> 3 blocks/CU.
// T4: counted vmcnt(5), raw s_barrier, trailing lgkmcnt(0) fence before
// buffer reuse. XOR swizzle on BOTH sides (rule #21): LDS[row][s] holds
// global slot s^(row&7); read with s=(kk*4+lk)^(lr&7) -> balanced banks.
__global__ __launch_bounds__(256, 3) void grouped_qkv(const short* __restrict__ x_bf,
                                                      const short* __restrict__ Wg,
                                                      const int* __restrict__ pairtok,
                                                      const int* __restrict__ cnt,
                                                      const float* __restrict__ rwb,
                                                      const float* __restrict__ decb,
                                                      float* __restrict__ rec) {
  const int bid = blockIdx.x;
  const int h = bid & 63;                             // h%8 == bid%8 (XCD affinity)
  const int c = bid >> 6;                             // 0..127 chunk of 64 rows
  const int n = cnt[h];
  if (c * 64 >= n) return;
  __shared__ __align__(16) short stg[2][10240];       // 40 KB: A[64][64] | B[96][64]
  __shared__ int prs[64];

  if (threadIdx.x < 64) {
    const int ri = c * 64 + threadIdx.x;
    prs[threadIdx.x] = (ri < n) ? pairtok[h * NTOK + ri] : -1;
  }
  __syncthreads();

  const int w = threadIdx.x >> 6, l = threadIdx.x & 63;
  const int lr = l & 15, lk = l >> 4;
  const int fallback = prs[0] >> 3;

  // staging decode: 8 rows/instr (lrow8), 8 slots of 16B (lslot), swizzled src
  const int lrow8 = l >> 3, lslot = l & 7;
  const int swz = (lslot ^ lrow8) << 3;               // shorts within 64-short row
  const int pA0 = prs[w * 16 + lrow8];
  const int pA1 = prs[w * 16 + 8 + lrow8];
  const short* sa0 = x_bf + (size_t)((pA0 >= 0) ? (pA0 >> 3) : fallback) * DIM_ + swz;
  const short* sa1 = x_bf + (size_t)((pA1 >= 0) ? (pA1 >> 3) : fallback) * DIM_ + swz;
  const short* sb  = Wg + ((size_t)h * 96 + w * 24 + lrow8) * DIM_ + swz;

  auto STAGE = [&](int s, int t) {                    // 5 loads/wave
    const int k0 = t * 64;
    short* bb = stg[s];
    gld_lds16(sa0 + k0, bb + (w * 16) * 64);
    gld_lds16(sa1 + k0, bb + (w * 16 + 8) * 64);
#pragma unroll
    for (int j = 0; j < 3; ++j)
      gld_lds16(sb + (size_t)(j * 8) * DIM_ + k0, bb + 4096 + (w * 24 + j * 8) * 64);
  };

  f32x4 acc[6] = {};
  STAGE(0, 0);
  int cur = 0;
  for (int t = 0; t < 16; ++t) {
    if (t < 15) {
      STAGE(cur ^ 1, t + 1);
      asm volatile("s_waitcnt vmcnt(5) lgkmcnt(0)" ::: "memory");
    } else {
      asm volatile("s_waitcnt vmcnt(0) lgkmcnt(0)" ::: "memory");
    }
    __builtin_amdgcn_s_barrier();
    __builtin_amdgcn_sched_barrier(0);
    const short* bb = stg[cur];
#pragma unroll
    for (int kk = 0; kk < 2; ++kk) {
      const int sl = ((kk * 4 + lk) ^ (lr & 7)) << 3;
      const bf16x8 a = *(const bf16x8*)(bb + (w * 16 + lr) * 64 + sl);
#pragma unroll
      for (int j = 0; j < 6; ++j) {
        const bf16x8 bj = *(const bf16x8*)(bb + 4096 + (j * 16 + lr) * 64 + sl);
        acc[j] = __builtin_amdgcn_mfma_f32_16x16x32_bf16(a, bj, acc[j], 0, 0, 0);
      }
    }
    asm volatile("s_waitcnt lgkmcnt(0)" ::: "memory"); // reads retired before reuse
    __builtin_amdgcn_sched_barrier(0);
    __builtin_amdgcn_s_barrier();
    cur ^= 1;
  }

  // epilogue: row = w*16 + lk*4 + r; acc cols j0,j1=q j2,j3=k j4,j5=v
#pragma unroll
  for (int r = 0; r < 4; ++r) {
    const int row = w * 16 + lk * 4 + r;
    const int p = prs[row];
    float q0v = silu_f(acc[0][r]), q1v = silu_f(acc[1][r]);
    float k0v = silu_f(acc[2][r]), k1v = silu_f(acc[3][r]);
    float v0 = silu_f(acc[4][r]), v1 = silu_f(acc[5][r]);
    float ssq = q0v * q0v + q1v * q1v;
    float ssk = k0v * k0v + k1v * k1v;
    ssq += __shfl_xor(ssq, 1); ssq += __shfl_xor(ssq, 2);
    ssq += __shfl_xor(ssq, 4); ssq += __shfl_xor(ssq, 8);
    ssk += __shfl_xor(ssk, 1); ssk += __shfl_xor(ssk, 2);
    ssk += __shfl_xor(ssk, 4); ssk += __shfl_xor(ssk, 8);
    const float rq = rsqrtf(ssq + 1e-6f), rk = rsqrtf(ssk + 1e-6f);
    if (p >= 0) {
      const int m = p >> 3, s = p & 7;
      const int b = m >> 11, t = m & (T_ - 1);
      float* rb = rec + (((size_t)(b * 8 + s)) * T_ + t) * 128;
      rb[lr]      = k0v * rk;
      rb[16 + lr] = k1v * rk;
      rb[32 + lr] = q0v * rq;
      rb[48 + lr] = q1v * rq;
      rb[64 + lr] = v0;
      rb[80 + lr] = v1;
      if (lr == 0) { rb[96] = decb[p]; rb[97] = rwb[p]; }
    }
  }
}

// ---------------------------------------------------------------- bf16 MFMA GEMM, C = A * B^T (final proj)
template <bool OUT_BF16>
__global__ __launch_bounds__(256) void gemm_bt(const short* __restrict__ A,
                                               const short* __restrict__ Bm,
                                               void* __restrict__ Cout,
                                               int M, int N, int K) {
  __shared__ __align__(16) short As[2][128 * 32];
  __shared__ __align__(16) short Bs[2][128 * 32];
  const int tid = threadIdx.x;
  const int w = tid >> 6, l = tid & 63;
  const int m0 = blockIdx.y * 128, n0 = blockIdx.x * 128;
  const int wr = (w >> 1) * 64, wc = (w & 1) * 64;
  const int rsub = l >> 2, csub = (l & 3) * 8;
  const int lr = l & 15, lk = l >> 4;
  f32x4 acc[4][4] = {};

  auto STAGE = [&](int buf, int k0) {
#pragma unroll
    for (int j = 0; j < 2; ++j) {
      const int ra = w * 32 + j * 16;
      gld_lds16(A  + (size_t)(m0 + ra + rsub) * K + k0 + csub, As[buf] + ra * 32);
      gld_lds16(Bm + (size_t)(n0 + ra + rsub) * K + k0 + csub, Bs[buf] + ra * 32);
    }
  };

  STAGE(0, 0);
  __syncthreads();
  int cur = 0;
  for (int k0 = 0; k0 < K; k0 += 32) {
    if (k0 + 32 < K) STAGE(cur ^ 1, k0 + 32);
    bf16x8 af[4], bfr[4];
#pragma unroll
    for (int i = 0; i < 4; ++i) af[i]  = *(const bf16x8*)(As[cur] + (wr + i * 16 + lr) * 32 + lk * 8);
#pragma unroll
    for (int j = 0; j < 4; ++j) bfr[j] = *(const bf16x8*)(Bs[cur] + (wc + j * 16 + lr) * 32 + lk * 8);
#pragma unroll
    for (int i = 0; i < 4; ++i)
#pragma unroll
      for (int j = 0; j < 4; ++j)
        acc[i][j] = __builtin_amdgcn_mfma_f32_16x16x32_bf16(af[i], bfr[j], acc[i][j], 0, 0, 0);
    __syncthreads();
    cur ^= 1;
  }
#pragma unroll
  for (int i = 0; i < 4; ++i)
#pragma unroll
    for (int j = 0; j < 4; ++j) {
      const size_t row0 = (size_t)m0 + wr + i * 16 + lk * 4;
      const size_t col  = (size_t)n0 + wc + j * 16 + lr;
#pragma unroll
      for (int r = 0; r < 4; ++r) {
        if constexpr (OUT_BF16)
          ((__hip_bfloat16*)Cout)[(row0 + r) * N + col] = __float2bfloat16(acc[i][j][r]);
        else
          ((float*)Cout)[(row0 + r) * N + col] = acc[i][j][r];
      }
    }
}

// ---------------------------------------------------------------- chunked scan: pass 1
__global__ __launch_bounds__(256) void scan_pass1(const float* __restrict__ rec,
                                                  float* __restrict__ ylocal,
                                                  float* __restrict__ Sloc,
                                                  float* __restrict__ Pc,
                                                  float* __restrict__ cumd) {
  __shared__ __align__(16) float R[CL_ * 128];   // 32 KB
  const int blk = blockIdx.x;
  const int bs = blk >> 5, c = blk & (NC_ - 1);
  const int t0 = c * CL_;
  const float* g = rec + ((size_t)bs * T_ + t0) * 128;
  for (int i = threadIdx.x; i < CL_ * 32; i += 256)
    *(float4*)(R + (size_t)i * 4) = *(const float4*)(g + (size_t)i * 4);
  __syncthreads();

  const int w = threadIdx.x >> 6, l = threadIdx.x & 63;
  const int v = w * 8 + (l & 7);
  const int n0 = (l >> 3) * 4;
  float s0 = 0.f, s1 = 0.f, s2 = 0.f, s3 = 0.f;
  float cum = 1.f;
  float* yl = ylocal + ((size_t)bs * T_ + t0) * 32 + v;
  float* cd = cumd + (size_t)bs * T_ + t0;

#pragma unroll 4
  for (int t = 0; t < CL_; ++t) {
    const float* r = R + t * 128;
    const float4 k4 = *(const float4*)(r + n0);
    const float4 q4 = *(const float4*)(r + 32 + n0);
    const float vv = r[64 + v];
    const float d  = r[96];
    cum *= d;
    s0 = fmaf(d, s0, k4.x * vv);
    s1 = fmaf(d, s1, k4.y * vv);
    s2 = fmaf(d, s2, k4.z * vv);
    s3 = fmaf(d, s3, k4.w * vv);
    float p = fmaf(q4.x, s0, fmaf(q4.y, s1, fmaf(q4.z, s2, q4.w * s3)));
    p += __shfl_xor(p, 8); p += __shfl_xor(p, 16); p += __shfl_xor(p, 32);
    if (l < 8) yl[(size_t)t * 32] = p;
    if (threadIdx.x == 0) cd[t] = cum;
  }
  float* sl = Sloc + (((size_t)bs * NC_ + c) * 32 + n0) * 32 + v;
  sl[0] = s0; sl[32] = s1; sl[64] = s2; sl[96] = s3;
  if (threadIdx.x == 0) Pc[bs * NC_ + c] = cum;
}

// ---------------------------------------------------------------- chunked scan: pass 2
__global__ __launch_bounds__(256) void scan_pass2(const float* __restrict__ Sloc,
                                                  const float* __restrict__ Pc,
                                                  const float* __restrict__ S0,
                                                  float* __restrict__ Sin,
                                                  float* __restrict__ Sfin) {
  __shared__ float Ps[NC_];
  const int bs = blockIdx.x;
  if (threadIdx.x < NC_) Ps[threadIdx.x] = Pc[bs * NC_ + threadIdx.x];
  __syncthreads();

  const int e0 = threadIdx.x * 4;
  const float* gl = Sloc + (size_t)bs * NC_ * 1024 + e0;
  float4 S = *(const float4*)(S0 + (size_t)bs * 1024 + e0);
  float* sin_b = Sin + (size_t)bs * NC_ * 1024 + e0;
#pragma unroll 8
  for (int c = 0; c < NC_; ++c) {
    const float4 sl = *(const float4*)(gl + (size_t)c * 1024);
    *(float4*)(sin_b + (size_t)c * 1024) = S;
    const float pc = Ps[c];
    S.x = fmaf(pc, S.x, sl.x);
    S.y = fmaf(pc, S.y, sl.y);
    S.z = fmaf(pc, S.z, sl.z);
    S.w = fmaf(pc, S.w, sl.w);
  }
  *(float4*)(Sfin + (size_t)bs * 1024 + e0) = S;
}

// ---------------------------------------------------------------- chunked scan: pass 3
__global__ __launch_bounds__(256) void scan_pass3(const float* __restrict__ rec,
                                                  const float* __restrict__ ylocal,
                                                  const float* __restrict__ Sin,
                                                  const float* __restrict__ cumd,
                                                  __hip_bfloat16* __restrict__ Y) {
  __shared__ __align__(16) float Ss[1024];
  const int blk = blockIdx.x;
  const int bs = blk >> 5, c = blk & (NC_ - 1);
  const int b = bs >> 3, s = bs & 7;
  const int t0 = c * CL_;
  {
    const float* gs = Sin + ((size_t)bs * NC_ + c) * 1024;
    const int i = threadIdx.x;
    *(float4*)(Ss + (size_t)i * 4) = *(const float4*)(gs + (size_t)i * 4);
  }
  __syncthreads();

  const int w = threadIdx.x >> 6, l = threadIdx.x & 63;
  const int v = l & 31;
#pragma unroll
  for (int i = 0; i < 16; i += 2) {
    const int t = t0 + w * 16 + i + (l >> 5);
    const float* r = rec + ((size_t)bs * T_ + t) * 128;
    float p = 0.f;
#pragma unroll
    for (int nq = 0; nq < 8; ++nq) {
      const float4 q4 = *(const float4*)(r + 32 + nq * 4);
      p = fmaf(q4.x, Ss[(nq * 4 + 0) * 32 + v], p);
      p = fmaf(q4.y, Ss[(nq * 4 + 1) * 32 + v], p);
      p = fmaf(q4.z, Ss[(nq * 4 + 2) * 32 + v], p);
      p = fmaf(q4.w, Ss[(nq * 4 + 3) * 32 + v], p);
    }
    const float wt   = r[97];
    const float cdv  = cumd[(size_t)bs * T_ + t];
    const float yloc = ylocal[((size_t)bs * T_ + t) * 32 + v];
    const long m = (long)b * T_ + t;
    Y[(size_t)m * 256 + s * 32 + v] = __float2bfloat16(wt * (yloc + cdv * p));
  }
}

// ---------------------------------------------------------------- launch
extern "C" void kernel_launch(void* const* d_in, const int* in_sizes, int n_in,
                              void* d_out, int out_size, void* d_ws, size_t ws_size,
                              hipStream_t stream) {
  const float* x       = (const float*)d_in[0];
  const float* Wr      = (const float*)d_in[1];
  const float* Wq      = (const float*)d_in[2];
  const float* Wk      = (const float*)d_in[3];
  const float* Wv      = (const float*)d_in[4];
  const float* Wa      = (const float*)d_in[5];
  const float* A_log   = (const float*)d_in[6];
  const float* dt_bias = (const float*)d_in[7];
  const float* Wo      = (const float*)d_in[8];
  const float* S0      = (const float*)d_in[9];
  float* out = (float*)d_out;

  char* p = (char*)d_ws;
  auto alloc = [&](size_t bytes) -> void* {
    void* r = (void*)p; p += (bytes + 255) & ~(size_t)255; return r;
  };
  __hip_bfloat16* x_bf = (__hip_bfloat16*)alloc((size_t)NTOK * DIM_ * 2);
  __hip_bfloat16* Wg   = (__hip_bfloat16*)alloc((size_t)H_ * 96 * DIM_ * 2);
  float* WT   = (float*)alloc((size_t)DIM_ * RA_N * 4);
  float* RA   = (float*)alloc((size_t)NTOK * RA_N * 4);
  int*   idxb = (int*)  alloc((size_t)NPAIR * 4);
  float* rwb  = (float*)alloc((size_t)NPAIR * 4);
  float* decb = (float*)alloc((size_t)NPAIR * 4);
  int*   cnt  = (int*)  alloc(256);
  int*   pairtok = (int*)alloc((size_t)H_ * NTOK * 4);
  float* recb = (float*)alloc((size_t)NSLOT * T_ * 128 * 4);
  __hip_bfloat16* Yb = (__hip_bfloat16*)alloc((size_t)NTOK * 256 * 2);
  __hip_bfloat16* B2 = (__hip_bfloat16*)alloc((size_t)DIM_ * 256 * 2);
  float* ylocal = (float*)alloc((size_t)NSLOT * T_ * 32 * 4);
  float* Slocb  = (float*)alloc((size_t)NSLOT * NC_ * 1024 * 4);
  float* Pcb    = (float*)alloc((size_t)NSLOT * NC_ * 4);
  float* Sinb   = (float*)alloc((size_t)NSLOT * NC_ * 1024 * 4);
  float* cumdb  = (float*)alloc((size_t)NSLOT * T_ * 4);

  cast_bf16<<<NTOK * DIM_ / 4 / 256, 256, 0, stream>>>(x, x_bf, NTOK * DIM_ / 4);
  build_wg<<<H_ * 96 * DIM_ / 4 / 256, 256, 0, stream>>>(Wq, Wk, Wv, Wg);
  build_b2<<<DIM_ * 256 / 256, 256, 0, stream>>>(Wo, B2);
  build_wt<<<DIM_ * RA_N / 256, 256, 0, stream>>>(Wr, Wa, WT);

  router_gemm<<<NTOK / 16, 256, 0, stream>>>(x, WT, RA);
  router_topk<<<NTOK / 4, 256, 0, stream>>>(RA, A_log, dt_bias, idxb, rwb, decb);

  zero_cnt<<<1, 64, 0, stream>>>(cnt);
  hist_bucket<<<32, 256, 0, stream>>>(idxb, cnt, pairtok);

  grouped_qkv<<<8192, 256, 0, stream>>>(
      (const short*)x_bf, (const short*)Wg, pairtok, cnt, rwb, decb, recb);

  scan_pass1<<<NSLOT * NC_, 256, 0, stream>>>(recb, ylocal, Slocb, Pcb, cumdb);
  scan_pass2<<<NSLOT, 256, 0, stream>>>(Slocb, Pcb, S0, Sinb, out + (size_t)NTOK * DIM_);
  scan_pass3<<<NSLOT * NC_, 256, 0, stream>>>(recb, ylocal, Sinb, cumdb, Yb);

  gemm_bt<false><<<dim3(DIM_ / 128, NTOK / 128), 256, 0, stream>>>(
      (const short*)Yb, (const short*)B2, out, NTOK, DIM_, 256);
}